// Round 2
// baseline (416.632 us; speedup 1.0000x reference)
//
#include <hip/hip_runtime.h>
#include <hip/hip_bf16.h>
#include <stdint.h>

// B=4, S=1024, D=1024, H=16, M=64, DH=64
#define SB 1024
#define DD 1024
#define NH 16
#define MM 64
#define DH 64

typedef __attribute__((ext_vector_type(8))) short s16x8;
typedef __attribute__((ext_vector_type(4))) float f32x4;

__device__ __forceinline__ unsigned short f2bf(float f) {
    union { float f; unsigned int u; } v; v.f = f;
    unsigned int u = v.u;
    u += 0x7FFFu + ((u >> 16) & 1u);
    return (unsigned short)(u >> 16);
}
__device__ __forceinline__ float bf2f(unsigned short h) {
    union { unsigned int u; float f; } v; v.u = ((unsigned int)h) << 16;
    return v.f;
}

// ---------------------------------------------------------------------------
// Transpose + convert the 4 weight matrices: Wt[n][k] = bf16(W[k][n])
// grid (32,32,4), block (32,8)
// ---------------------------------------------------------------------------
__global__ __launch_bounds__(256) void wtrans_kernel(const float* W0, const float* W1,
                                                     const float* W2, const float* W3,
                                                     unsigned short* out) {
    const float* W = (blockIdx.z == 0) ? W0 : (blockIdx.z == 1) ? W1 : (blockIdx.z == 2) ? W2 : W3;
    unsigned short* Wt = out + (size_t)blockIdx.z * (size_t)DD * DD;
    __shared__ float tile[32][33];
    const int tx = threadIdx.x, ty = threadIdx.y;
    const int x0 = blockIdx.x * 32, y0 = blockIdx.y * 32;
#pragma unroll
    for (int j = 0; j < 4; ++j)
        tile[ty + 8 * j][tx] = W[(size_t)(y0 + ty + 8 * j) * DD + x0 + tx];
    __syncthreads();
#pragma unroll
    for (int j = 0; j < 4; ++j)
        Wt[(size_t)(x0 + ty + 8 * j) * DD + y0 + tx] = f2bf(tile[tx][ty + 8 * j]);
}

// ---------------------------------------------------------------------------
// GEMM: C[4096,1024] = A[4096,1024] @ Bt[1024(n),1024(k)]^T-stored, bf16 MFMA
// AMODE 0: A is f32 (convert on stage)   AMODE 1: A is bf16
// OMODE 0: head-split bf16  -> out[((b*16+h)*1024+s)*64+dh]
// OMODE 1: v-transposed bf16 -> out[((b*16+h)*64+dh)*1024+s]
// OMODE 2: f32 flat          -> out[r*1024+c]
// tiles 128x128, BK=32, 256 threads (4 waves, 2x2, each 64x64)
// ---------------------------------------------------------------------------
template <int AMODE, int OMODE>
__global__ __launch_bounds__(256) void gemm_kernel(const void* Ap, const unsigned short* Bt,
                                                   void* outp) {
    __shared__ unsigned short As[128][40];
    __shared__ unsigned short Bs[128][40];
    const int tid = threadIdx.x;
    const int l = tid & 63;
    const int w = tid >> 6;
    const int m0b = blockIdx.y * 128;
    const int n0b = blockIdx.x * 128;
    const int wm = (w >> 1) * 64;
    const int wn = (w & 1) * 64;
    const int l15 = l & 15;
    const int lq = l >> 4;

    f32x4 acc[4][4];
#pragma unroll
    for (int i = 0; i < 4; ++i)
#pragma unroll
        for (int j = 0; j < 4; ++j) acc[i][j] = (f32x4){0.f, 0.f, 0.f, 0.f};

    for (int kt = 0; kt < DD / 32; ++kt) {
        const int k0 = kt * 32;
        __syncthreads();
#pragma unroll
        for (int j = 0; j < 2; ++j) {
            const int chunk = j * 256 + tid;
            const int row = chunk >> 2, cc = chunk & 3;
            if (AMODE == 0) {
                const float* Af = (const float*)Ap;
                const f32x4* src = (const f32x4*)(Af + (size_t)(m0b + row) * DD + k0 + cc * 8);
                f32x4 u0 = src[0], u1 = src[1];
                s16x8 t;
                t[0] = (short)f2bf(u0[0]); t[1] = (short)f2bf(u0[1]);
                t[2] = (short)f2bf(u0[2]); t[3] = (short)f2bf(u0[3]);
                t[4] = (short)f2bf(u1[0]); t[5] = (short)f2bf(u1[1]);
                t[6] = (short)f2bf(u1[2]); t[7] = (short)f2bf(u1[3]);
                *(s16x8*)(&As[row][cc * 8]) = t;
            } else {
                const unsigned short* Ab = (const unsigned short*)Ap;
                *(s16x8*)(&As[row][cc * 8]) =
                    *(const s16x8*)(Ab + (size_t)(m0b + row) * DD + k0 + cc * 8);
            }
            *(s16x8*)(&Bs[row][cc * 8]) =
                *(const s16x8*)(Bt + (size_t)(n0b + row) * DD + k0 + cc * 8);
        }
        __syncthreads();

        s16x8 af[4], bfr[4];
#pragma unroll
        for (int mi = 0; mi < 4; ++mi)
            af[mi] = *(const s16x8*)(&As[wm + mi * 16 + l15][8 * lq]);
#pragma unroll
        for (int ni = 0; ni < 4; ++ni)
            bfr[ni] = *(const s16x8*)(&Bs[wn + ni * 16 + l15][8 * lq]);
#pragma unroll
        for (int mi = 0; mi < 4; ++mi)
#pragma unroll
            for (int ni = 0; ni < 4; ++ni)
                acc[mi][ni] = __builtin_amdgcn_mfma_f32_16x16x32_bf16(af[mi], bfr[ni],
                                                                      acc[mi][ni], 0, 0, 0);
    }

    const int row4 = lq * 4;
#pragma unroll
    for (int mi = 0; mi < 4; ++mi)
#pragma unroll
        for (int ni = 0; ni < 4; ++ni)
#pragma unroll
            for (int i = 0; i < 4; ++i) {
                const int r = m0b + wm + mi * 16 + row4 + i;  // global row = b*1024+s
                const int c = n0b + wn + ni * 16 + l15;       // global col
                const float v = acc[mi][ni][i];
                if (OMODE == 2) {
                    ((float*)outp)[(size_t)r * DD + c] = v;
                } else {
                    const int b = r >> 10, s = r & 1023;
                    const int h = c >> 6, dh = c & 63;
                    if (OMODE == 0)
                        ((unsigned short*)outp)[((size_t)((b * NH + h) * SB + s)) * DH + dh] = f2bf(v);
                    else
                        ((unsigned short*)outp)[((size_t)((b * NH + h) * DH + dh)) * SB + s] = f2bf(v);
                }
            }
}

// ---------------------------------------------------------------------------
// mult[b][q][k] = alpha * dot(q_mult[b][q][:], kv_mult[b][k][:])  (f32 out)
// plus per-batch sum-of-squares atomicAdd into fro_acc[b].
// grid (64, 4), block 256 (4 waves; wave w covers k in [w*256, w*256+256))
// ---------------------------------------------------------------------------
__global__ __launch_bounds__(256) void mult_kernel(const float* qm, const float* kvm,
                                                   const float* alpha_p, float* mult_out,
                                                   float* fro_acc) {
    const int b = blockIdx.y;
    const int q0 = blockIdx.x * 16;
    const int tid = threadIdx.x, l = tid & 63, w = tid >> 6;
    const int l15 = l & 15, lq = l >> 4;
    const float alpha = alpha_p[0];

    s16x8 a[2];
#pragma unroll
    for (int kt = 0; kt < 2; ++kt) {
        const float* src = qm + ((size_t)b * SB + q0 + l15) * MM + kt * 32 + 8 * lq;
        s16x8 t;
#pragma unroll
        for (int i = 0; i < 8; ++i) t[i] = (short)f2bf(src[i]);
        a[kt] = t;
    }
    float ss = 0.f;
    for (int nt = 0; nt < 16; ++nt) {
        const int n0 = w * 256 + nt * 16;
        f32x4 acc = (f32x4){0.f, 0.f, 0.f, 0.f};
#pragma unroll
        for (int kt = 0; kt < 2; ++kt) {
            const float* src = kvm + ((size_t)b * SB + n0 + l15) * MM + kt * 32 + 8 * lq;
            s16x8 t;
#pragma unroll
            for (int i = 0; i < 8; ++i) t[i] = (short)f2bf(src[i]);
            acc = __builtin_amdgcn_mfma_f32_16x16x32_bf16(a[kt], t, acc, 0, 0, 0);
        }
#pragma unroll
        for (int i = 0; i < 4; ++i) {
            const float v = acc[i] * alpha;
            const int r = lq * 4 + i;
            mult_out[((size_t)b * SB + q0 + r) * SB + n0 + l15] = v;
            ss += v * v;
        }
    }
#pragma unroll
    for (int mk = 1; mk < 64; mk <<= 1) ss += __shfl_xor(ss, mk);
    __shared__ float wss[4];
    if (l == 0) wss[w] = ss;
    __syncthreads();
    if (tid == 0) atomicAdd(fro_acc + b, wss[0] + wss[1] + wss[2] + wss[3]);
}

// ---------------------------------------------------------------------------
// Fused attention: per block = (b, h, 16 q-rows).
// scores (MFMA, kh B-frags from global) -> LDS bf16 (XOR-swizzled) ->
// masked softmax (wave-parallel) + mult/fro -> PV (MFMA, vht B-frags global)
// grid (64, 64), block 256
// ---------------------------------------------------------------------------
__global__ __launch_bounds__(256) void attn_kernel(const unsigned short* qh, const unsigned short* kh,
                                                   const unsigned short* vht, const float* mult,
                                                   const float* fro_acc, const int* valid_lens,
                                                   unsigned short* attn_out) {
    const int bh = blockIdx.y;
    const int b = bh >> 4, h = bh & 15;
    const int q0 = blockIdx.x * 16;
    const int tid = threadIdx.x, l = tid & 63, w = tid >> 6;
    const int l15 = l & 15, lq = l >> 4;
    const int vl = valid_lens[b];
    const float inv_fro = 1.f / (sqrtf(fro_acc[b]) + 1e-5f);

    __shared__ unsigned short attn_s[16][1024];  // 32 KB, granule-swizzled: elem ^= (row&7)<<3

    s16x8 a[2];
#pragma unroll
    for (int kt = 0; kt < 2; ++kt)
        a[kt] = *(const s16x8*)(qh + ((size_t)bh * SB + q0 + l15) * DH + kt * 32 + 8 * lq);

    const float scale = 0.125f;  // 1/sqrt(64)
    for (int nt = 0; nt < 16; ++nt) {
        const int n0 = w * 256 + nt * 16;
        f32x4 acc = (f32x4){0.f, 0.f, 0.f, 0.f};
#pragma unroll
        for (int kt = 0; kt < 2; ++kt) {
            s16x8 bfr = *(const s16x8*)(kh + ((size_t)bh * SB + n0 + l15) * DH + kt * 32 + 8 * lq);
            acc = __builtin_amdgcn_mfma_f32_16x16x32_bf16(a[kt], bfr, acc, 0, 0, 0);
        }
#pragma unroll
        for (int i = 0; i < 4; ++i) {
            const int r = lq * 4 + i;
            const int c = n0 + l15;
            attn_s[r][c ^ ((r & 7) << 3)] = f2bf(acc[i] * scale);
        }
    }
    __syncthreads();

    // softmax: wave w owns rows w*4+lq, 16 lanes per row, strided 8-elem granules
    {
        const int r = w * 4 + lq;
        const int g = l15;
        const int sw = r & 7;
        float mx = -3.0e38f;
        for (int j = 0; j < 8; ++j) {
            const int cc = g + 16 * j;       // true granule index
            const int base = cc * 8;
            if (base >= vl) continue;
            s16x8 vv = *(const s16x8*)(&attn_s[r][(cc ^ sw) * 8]);
#pragma unroll
            for (int e = 0; e < 8; ++e)
                if (base + e < vl) mx = fmaxf(mx, bf2f((unsigned short)vv[e]));
        }
#pragma unroll
        for (int mk = 1; mk < 16; mk <<= 1) mx = fmaxf(mx, __shfl_xor(mx, mk));
        float sum = 0.f;
        for (int j = 0; j < 8; ++j) {
            const int cc = g + 16 * j;
            const int base = cc * 8;
            if (base >= vl) continue;
            unsigned short* p = &attn_s[r][(cc ^ sw) * 8];
            s16x8 vv = *(const s16x8*)p;
            s16x8 ee;
#pragma unroll
            for (int e = 0; e < 8; ++e) {
                float f = 0.f;
                if (base + e < vl) { f = __expf(bf2f((unsigned short)vv[e]) - mx); sum += f; }
                ee[e] = (short)f2bf(f);
            }
            *(s16x8*)p = ee;
        }
#pragma unroll
        for (int mk = 1; mk < 16; mk <<= 1) sum += __shfl_xor(sum, mk);
        const float rinv = 1.f / sum;
        const float* mrow = mult + ((size_t)b * SB + q0 + r) * SB;
        for (int j = 0; j < 8; ++j) {
            const int cc = g + 16 * j;
            const int base = cc * 8;
            unsigned short* p = &attn_s[r][(cc ^ sw) * 8];
            s16x8 vv = *(const s16x8*)p;
            s16x8 oo;
#pragma unroll
            for (int e = 0; e < 8; ++e) {
                const int kk = base + e;
                float pr = (kk < vl) ? bf2f((unsigned short)vv[e]) * rinv : 0.f;
                pr += mrow[kk] * inv_fro;
                oo[e] = (short)f2bf(pr);
            }
            *(s16x8*)p = oo;
        }
    }
    __syncthreads();

    // PV: wave w -> dh columns [w*16, w*16+16)
    const int dh0 = w * 16;
    f32x4 oacc = (f32x4){0.f, 0.f, 0.f, 0.f};
    for (int kt = 0; kt < 32; ++kt) {
        const int r = l15;
        const int kbase = kt * 32 + 8 * lq;
        const int cc = (kbase >> 3) ^ (r & 7);
        s16x8 af = *(const s16x8*)(&attn_s[r][cc * 8]);
        s16x8 bfr = *(const s16x8*)(vht + ((size_t)bh * DH + dh0 + l15) * SB + kbase);
        oacc = __builtin_amdgcn_mfma_f32_16x16x32_bf16(af, bfr, oacc, 0, 0, 0);
    }
#pragma unroll
    for (int i = 0; i < 4; ++i) {
        const int r = lq * 4 + i;
        attn_out[((size_t)b * SB + q0 + r) * DD + h * DH + dh0 + l15] = f2bf(oacc[i]);
    }
}

// ---------------------------------------------------------------------------
extern "C" void kernel_launch(void* const* d_in, const int* in_sizes, int n_in,
                              void* d_out, int out_size, void* d_ws, size_t ws_size,
                              hipStream_t stream) {
    const float* q   = (const float*)d_in[0];
    const float* k   = (const float*)d_in[1];
    const float* v   = (const float*)d_in[2];
    const float* qm  = (const float*)d_in[3];
    const float* kvm = (const float*)d_in[4];
    const int* vl    = (const int*)d_in[5];
    const float* Wq  = (const float*)d_in[6];
    const float* Wk  = (const float*)d_in[7];
    const float* Wv  = (const float*)d_in[8];
    const float* Wo  = (const float*)d_in[9];
    const float* alpha = (const float*)d_in[10];

    char* ws = (char*)d_ws;
    unsigned short* Wt   = (unsigned short*)(ws);                       // 4 x 2MB
    unsigned short* qh   = (unsigned short*)(ws + (size_t)(8u << 20));  // 8MB
    unsigned short* khp  = (unsigned short*)(ws + (size_t)(16u << 20)); // 8MB
    unsigned short* vht  = (unsigned short*)(ws + (size_t)(24u << 20)); // 8MB
    float* multp         = (float*)(ws + (size_t)(32u << 20));          // 16MB
    float* fro           = (float*)(ws + (size_t)(48u << 20));          // 16B
    unsigned short* aout = (unsigned short*)(ws + (size_t)(48u << 20) + 256); // 8MB

    hipMemsetAsync(fro, 0, 4 * sizeof(float), stream);

    wtrans_kernel<<<dim3(32, 32, 4), dim3(32, 8, 1), 0, stream>>>(Wq, Wk, Wv, Wo, Wt);

    const dim3 gb(8, 32, 1);
    gemm_kernel<0, 0><<<gb, 256, 0, stream>>>(q, Wt + 0 * (1u << 20), qh);
    gemm_kernel<0, 0><<<gb, 256, 0, stream>>>(k, Wt + 1 * (1u << 20), khp);
    gemm_kernel<0, 1><<<gb, 256, 0, stream>>>(v, Wt + 2 * (1u << 20), vht);

    mult_kernel<<<dim3(64, 4, 1), 256, 0, stream>>>(qm, kvm, alpha, multp, fro);
    attn_kernel<<<dim3(64, 64, 1), 256, 0, stream>>>(qh, khp, vht, multp, fro, vl, aout);
    gemm_kernel<1, 2><<<gb, 256, 0, stream>>>(aout, Wt + 3 * (1u << 20), d_out);
}

// Round 3
// 350.454 us; speedup vs baseline: 1.1888x; 1.1888x over previous
//
#include <hip/hip_runtime.h>
#include <hip/hip_bf16.h>
#include <stdint.h>

// B=4, S=1024, D=1024, H=16, M=64, DH=64
#define SB 1024
#define DD 1024
#define NH 16
#define MM 64
#define DHD 64

typedef __attribute__((ext_vector_type(8))) short s16x8;
typedef __attribute__((ext_vector_type(4))) float f32x4;

__device__ __forceinline__ unsigned short f2bf(float f) {
    union { float f; unsigned int u; } v; v.f = f;
    unsigned int u = v.u;
    u += 0x7FFFu + ((u >> 16) & 1u);
    return (unsigned short)(u >> 16);
}
__device__ __forceinline__ float bf2f(unsigned short h) {
    union { unsigned int u; float f; } v; v.u = ((unsigned int)h) << 16;
    return v.f;
}

__device__ __forceinline__ void gload_lds16(const unsigned short* g, unsigned short* l) {
    __builtin_amdgcn_global_load_lds(
        (const __attribute__((address_space(1))) unsigned int*)g,
        (__attribute__((address_space(3))) unsigned int*)l, 16, 0, 0);
}

// ---------------------------------------------------------------------------
// q,k,v f32 -> bf16 copies. grid (2048, 3), block 256, 8 elems/thread.
// ---------------------------------------------------------------------------
__global__ __launch_bounds__(256) void cvt_kernel(const float* q, const float* k, const float* v,
                                                  unsigned short* qb, unsigned short* kb,
                                                  unsigned short* vb) {
    const int z = blockIdx.y;
    const float* src = (z == 0) ? q : (z == 1) ? k : v;
    unsigned short* dst = (z == 0) ? qb : (z == 1) ? kb : vb;
    const size_t base = ((size_t)blockIdx.x * 256 + threadIdx.x) * 8;
    f32x4 a = *(const f32x4*)(src + base);
    f32x4 b2 = *(const f32x4*)(src + base + 4);
    s16x8 t;
    t[0] = (short)f2bf(a[0]);  t[1] = (short)f2bf(a[1]);
    t[2] = (short)f2bf(a[2]);  t[3] = (short)f2bf(a[3]);
    t[4] = (short)f2bf(b2[0]); t[5] = (short)f2bf(b2[1]);
    t[6] = (short)f2bf(b2[2]); t[7] = (short)f2bf(b2[3]);
    *(s16x8*)(dst + base) = t;
}

// ---------------------------------------------------------------------------
// Transpose + convert the 4 weight matrices: Wt[n][k] = bf16(W[k][n])
// grid (32,32,4), block (32,8)
// ---------------------------------------------------------------------------
__global__ __launch_bounds__(256) void wtrans_kernel(const float* W0, const float* W1,
                                                     const float* W2, const float* W3,
                                                     unsigned short* out) {
    const float* W = (blockIdx.z == 0) ? W0 : (blockIdx.z == 1) ? W1 : (blockIdx.z == 2) ? W2 : W3;
    unsigned short* Wt = out + (size_t)blockIdx.z * (size_t)DD * DD;
    __shared__ float tile[32][33];
    const int tx = threadIdx.x, ty = threadIdx.y;
    const int x0 = blockIdx.x * 32, y0 = blockIdx.y * 32;
#pragma unroll
    for (int j = 0; j < 4; ++j)
        tile[ty + 8 * j][tx] = W[(size_t)(y0 + ty + 8 * j) * DD + x0 + tx];
    __syncthreads();
#pragma unroll
    for (int j = 0; j < 4; ++j)
        Wt[(size_t)(x0 + ty + 8 * j) * DD + y0 + tx] = f2bf(tile[tx][ty + 8 * j]);
}

// ---------------------------------------------------------------------------
// GEMM: C[4096,1024] = A[4096,1024](bf16) @ Bt[n][k](bf16, transposed-stored)
// 128x128 tile, BK=64, 512 threads (8 waves, 4x2), global_load_lds(16) staging
// with XOR-swizzled source (granule ^= row&7), 2-phase double-buffer pipeline.
// OMODE 0: head-split bf16; 1: v-transposed bf16; 2: f32 flat.
// ---------------------------------------------------------------------------
template <int OMODE>
__global__ __launch_bounds__(512) void gemm_kernel(const unsigned short* A, const unsigned short* Bt,
                                                   void* outp) {
    __shared__ unsigned short lds[2][2][128][64];  // [buf][A/B][row][col] 64KB
    const int tid = threadIdx.x, l = tid & 63, w = tid >> 6;
    const int l15 = l & 15, lq = l >> 4;
    const int m0b = blockIdx.y * 128, n0b = blockIdx.x * 128;
    const int wm = (w >> 1) * 32, wn = (w & 1) * 64;
    const int ric = l >> 3;                // row within 8-row chunk
    const int gsrc = (l & 7) ^ (ric & 7);  // pre-swizzled source granule

    f32x4 acc[2][4];
#pragma unroll
    for (int i = 0; i < 2; ++i)
#pragma unroll
        for (int j = 0; j < 4; ++j) acc[i][j] = (f32x4){0.f, 0.f, 0.f, 0.f};

    auto STAGE = [&](int bb, int kt) {
        const int k0 = kt * 64;
#pragma unroll
        for (int j = 0; j < 2; ++j) {
            const int chunk = w * 2 + j;
            const int r = chunk * 8 + ric;
            gload_lds16(A + (size_t)(m0b + r) * DD + k0 + gsrc * 8, &lds[bb][0][chunk * 8][0]);
            gload_lds16(Bt + (size_t)(n0b + r) * DD + k0 + gsrc * 8, &lds[bb][1][chunk * 8][0]);
        }
    };

    STAGE(0, 0);
    __syncthreads();
    int cur = 0;
    for (int kt = 0; kt < 16; ++kt) {
        if (kt < 15) STAGE(cur ^ 1, kt + 1);
#pragma unroll
        for (int kt2 = 0; kt2 < 2; ++kt2) {
            s16x8 af[2], bf[4];
#pragma unroll
            for (int mi = 0; mi < 2; ++mi) {
                const int R = wm + mi * 16 + l15;
                af[mi] = *(const s16x8*)(&lds[cur][0][R][((kt2 * 4 + lq) ^ (R & 7)) * 8]);
            }
#pragma unroll
            for (int ni = 0; ni < 4; ++ni) {
                const int R = wn + ni * 16 + l15;
                bf[ni] = *(const s16x8*)(&lds[cur][1][R][((kt2 * 4 + lq) ^ (R & 7)) * 8]);
            }
#pragma unroll
            for (int mi = 0; mi < 2; ++mi)
#pragma unroll
                for (int ni = 0; ni < 4; ++ni)
                    acc[mi][ni] = __builtin_amdgcn_mfma_f32_16x16x32_bf16(af[mi], bf[ni],
                                                                          acc[mi][ni], 0, 0, 0);
        }
        __syncthreads();
        cur ^= 1;
    }

#pragma unroll
    for (int mi = 0; mi < 2; ++mi)
#pragma unroll
        for (int ni = 0; ni < 4; ++ni)
#pragma unroll
            for (int i = 0; i < 4; ++i) {
                const int r = m0b + wm + mi * 16 + lq * 4 + i;
                const int c = n0b + wn + ni * 16 + l15;
                const float vv = acc[mi][ni][i];
                if (OMODE == 2) {
                    ((float*)outp)[(size_t)r * DD + c] = vv;
                } else {
                    const int b = r >> 10, s = r & 1023;
                    const int hh = c >> 6, dh = c & 63;
                    if (OMODE == 0)
                        ((unsigned short*)outp)[((size_t)((b * NH + hh) * SB + s)) * DHD + dh] = f2bf(vv);
                    else
                        ((unsigned short*)outp)[((size_t)((b * NH + hh) * DHD + dh)) * SB + s] = f2bf(vv);
                }
            }
}

// ---------------------------------------------------------------------------
// U[bh] = vht[bh] (64dh x 1024s) @ kvm[b] (1024s x 64m) -> bf16 [dh][m]
// grid 64, block 256 (4 waves split s into 256-strips), LDS partial reduce.
// ---------------------------------------------------------------------------
__global__ __launch_bounds__(256) void uk_kernel(const unsigned short* vht, const float* kvm,
                                                 unsigned short* U) {
    const int bh = blockIdx.x, b = bh >> 4;
    const int tid = threadIdx.x, l = tid & 63, w = tid >> 6;
    const int l15 = l & 15, lq = l >> 4;
    __shared__ float part[4][64][64];

    f32x4 acc[4][4];
#pragma unroll
    for (int i = 0; i < 4; ++i)
#pragma unroll
        for (int j = 0; j < 4; ++j) acc[i][j] = (f32x4){0.f, 0.f, 0.f, 0.f};

    for (int kt2 = 0; kt2 < 8; ++kt2) {
        const int sbase = w * 256 + kt2 * 32 + 8 * lq;
        s16x8 av[4], bk[4];
#pragma unroll
        for (int t = 0; t < 4; ++t)
            av[t] = *(const s16x8*)(vht + ((size_t)bh * DHD + t * 16 + l15) * SB + sbase);
#pragma unroll
        for (int t = 0; t < 4; ++t) {
            s16x8 tmp;
#pragma unroll
            for (int j = 0; j < 8; ++j)
                tmp[j] = (short)f2bf(kvm[((size_t)b * SB + sbase + j) * MM + t * 16 + l15]);
            bk[t] = tmp;
        }
#pragma unroll
        for (int at = 0; at < 4; ++at)
#pragma unroll
            for (int bt = 0; bt < 4; ++bt)
                acc[at][bt] = __builtin_amdgcn_mfma_f32_16x16x32_bf16(av[at], bk[bt],
                                                                      acc[at][bt], 0, 0, 0);
    }
#pragma unroll
    for (int at = 0; at < 4; ++at)
#pragma unroll
        for (int bt = 0; bt < 4; ++bt)
#pragma unroll
            for (int i = 0; i < 4; ++i)
                part[w][at * 16 + lq * 4 + i][bt * 16 + l15] = acc[at][bt][i];
    __syncthreads();
    for (int e = tid * 16; e < tid * 16 + 16; ++e) {
        const int r = e >> 6, c = e & 63;
        U[(size_t)bh * 4096 + e] =
            f2bf(part[0][r][c] + part[1][r][c] + part[2][r][c] + part[3][r][c]);
    }
}

// ---------------------------------------------------------------------------
// cscale[b] = alpha / (sqrt(alpha^2 * sum(Gq o Gk)) + 1e-5)
// Gq = qm^T@qm, Gk = kvm^T@kvm (64x64). grid 4, block 256.
// ---------------------------------------------------------------------------
__global__ __launch_bounds__(256) void gram_kernel(const float* qm, const float* kvm,
                                                   const float* alpha_p, float* cscale) {
    const int b = blockIdx.x;
    const int tid = threadIdx.x, l = tid & 63, w = tid >> 6;
    const int l15 = l & 15, lq = l >> 4;
    __shared__ float part[4][64][64];
    __shared__ float gq[64][64];
    __shared__ float red[4];

    // phase 1: Gq
    f32x4 acc[4][4];
#pragma unroll
    for (int i = 0; i < 4; ++i)
#pragma unroll
        for (int j = 0; j < 4; ++j) acc[i][j] = (f32x4){0.f, 0.f, 0.f, 0.f};
    for (int kt2 = 0; kt2 < 8; ++kt2) {
        const int sbase = w * 256 + kt2 * 32 + 8 * lq;
        s16x8 fq[4];
#pragma unroll
        for (int t = 0; t < 4; ++t) {
            s16x8 tmp;
#pragma unroll
            for (int j = 0; j < 8; ++j)
                tmp[j] = (short)f2bf(qm[((size_t)b * SB + sbase + j) * MM + t * 16 + l15]);
            fq[t] = tmp;
        }
#pragma unroll
        for (int at = 0; at < 4; ++at)
#pragma unroll
            for (int bt = 0; bt < 4; ++bt)
                acc[at][bt] = __builtin_amdgcn_mfma_f32_16x16x32_bf16(fq[at], fq[bt],
                                                                     acc[at][bt], 0, 0, 0);
    }
#pragma unroll
    for (int at = 0; at < 4; ++at)
#pragma unroll
        for (int bt = 0; bt < 4; ++bt)
#pragma unroll
            for (int i = 0; i < 4; ++i)
                part[w][at * 16 + lq * 4 + i][bt * 16 + l15] = acc[at][bt][i];
    __syncthreads();
    for (int e = tid * 16; e < tid * 16 + 16; ++e) {
        const int r = e >> 6, c = e & 63;
        gq[r][c] = part[0][r][c] + part[1][r][c] + part[2][r][c] + part[3][r][c];
    }
    __syncthreads();

    // phase 2: Gk + dot with Gq
#pragma unroll
    for (int i = 0; i < 4; ++i)
#pragma unroll
        for (int j = 0; j < 4; ++j) acc[i][j] = (f32x4){0.f, 0.f, 0.f, 0.f};
    for (int kt2 = 0; kt2 < 8; ++kt2) {
        const int sbase = w * 256 + kt2 * 32 + 8 * lq;
        s16x8 fk[4];
#pragma unroll
        for (int t = 0; t < 4; ++t) {
            s16x8 tmp;
#pragma unroll
            for (int j = 0; j < 8; ++j)
                tmp[j] = (short)f2bf(kvm[((size_t)b * SB + sbase + j) * MM + t * 16 + l15]);
            fk[t] = tmp;
        }
#pragma unroll
        for (int at = 0; at < 4; ++at)
#pragma unroll
            for (int bt = 0; bt < 4; ++bt)
                acc[at][bt] = __builtin_amdgcn_mfma_f32_16x16x32_bf16(fk[at], fk[bt],
                                                                     acc[at][bt], 0, 0, 0);
    }
#pragma unroll
    for (int at = 0; at < 4; ++at)
#pragma unroll
        for (int bt = 0; bt < 4; ++bt)
#pragma unroll
            for (int i = 0; i < 4; ++i)
                part[w][at * 16 + lq * 4 + i][bt * 16 + l15] = acc[at][bt][i];
    __syncthreads();
    float ss = 0.f;
    for (int e = tid * 16; e < tid * 16 + 16; ++e) {
        const int r = e >> 6, c = e & 63;
        const float gk = part[0][r][c] + part[1][r][c] + part[2][r][c] + part[3][r][c];
        ss += gk * gq[r][c];
    }
#pragma unroll
    for (int mk = 1; mk < 64; mk <<= 1) ss += __shfl_xor(ss, mk);
    if (l == 0) red[w] = ss;
    __syncthreads();
    if (tid == 0) {
        const float S = red[0] + red[1] + red[2] + red[3];
        const float a = alpha_p[0];
        cscale[b] = a / (sqrtf(a * a * S) + 1e-5f);
    }
}

// ---------------------------------------------------------------------------
// Fused attention: block = (bh, 32 q-rows), 8 waves (512 thr).
// QK in registers (wave w -> key strip w*128..+128), reg strip-max/sum +
// LDS cross-wave reduce, unnormalized exp -> swizzled P (bf16, 64KB LDS),
// PV k-split + X bias (qm@U^T) MFMA, rinv & cscale applied in epilogue.
// grid (32, 64)
// ---------------------------------------------------------------------------
__global__ __launch_bounds__(512) void attn_kernel(const unsigned short* qh, const unsigned short* kh,
                                                   const unsigned short* vht, const unsigned short* U,
                                                   const float* cscale, const float* qm,
                                                   const int* valid_lens, unsigned short* aout) {
    const int bh = blockIdx.y, b = bh >> 4, h = bh & 15;
    const int q0 = blockIdx.x * 32;
    const int tid = threadIdx.x, l = tid & 63, w = tid >> 6;
    const int l15 = l & 15, lq = l >> 4;
    const int vl = valid_lens[b];
    const float cs = cscale[b];

    __shared__ unsigned short P[32][1024];  // swizzled: elem ^= 8*(row&7)
    __shared__ float wmax[32][8];
    __shared__ float wsum[32][8];

    // ---- QK^T ----
    s16x8 aq[2][2];
#pragma unroll
    for (int mt = 0; mt < 2; ++mt)
#pragma unroll
        for (int kt = 0; kt < 2; ++kt)
            aq[mt][kt] = *(const s16x8*)(qh + ((size_t)bh * SB + q0 + mt * 16 + l15) * DHD +
                                         kt * 32 + 8 * lq);
    f32x4 sacc[2][8];
#pragma unroll
    for (int mt = 0; mt < 2; ++mt)
#pragma unroll
        for (int nt = 0; nt < 8; ++nt) sacc[mt][nt] = (f32x4){0.f, 0.f, 0.f, 0.f};
#pragma unroll
    for (int nt = 0; nt < 8; ++nt) {
        const int key = w * 128 + nt * 16 + l15;
        const unsigned short* kp = kh + ((size_t)bh * SB + key) * DHD + 8 * lq;
        s16x8 b0 = *(const s16x8*)(kp);
        s16x8 b1 = *(const s16x8*)(kp + 32);
        sacc[0][nt] = __builtin_amdgcn_mfma_f32_16x16x32_bf16(aq[0][0], b0, sacc[0][nt], 0, 0, 0);
        sacc[0][nt] = __builtin_amdgcn_mfma_f32_16x16x32_bf16(aq[0][1], b1, sacc[0][nt], 0, 0, 0);
        sacc[1][nt] = __builtin_amdgcn_mfma_f32_16x16x32_bf16(aq[1][0], b0, sacc[1][nt], 0, 0, 0);
        sacc[1][nt] = __builtin_amdgcn_mfma_f32_16x16x32_bf16(aq[1][1], b1, sacc[1][nt], 0, 0, 0);
    }

    // ---- strip max (registers) -> LDS cross-wave ----
    float mxp[2][4];
#pragma unroll
    for (int mt = 0; mt < 2; ++mt)
#pragma unroll
        for (int i = 0; i < 4; ++i) mxp[mt][i] = -3.0e38f;
#pragma unroll
    for (int nt = 0; nt < 8; ++nt) {
        const int col = w * 128 + nt * 16 + l15;
        if (col < vl) {
#pragma unroll
            for (int mt = 0; mt < 2; ++mt)
#pragma unroll
                for (int i = 0; i < 4; ++i)
                    mxp[mt][i] = fmaxf(mxp[mt][i], sacc[mt][nt][i]);
        }
    }
#pragma unroll
    for (int mk = 1; mk < 16; mk <<= 1)
#pragma unroll
        for (int mt = 0; mt < 2; ++mt)
#pragma unroll
            for (int i = 0; i < 4; ++i)
                mxp[mt][i] = fmaxf(mxp[mt][i], __shfl_xor(mxp[mt][i], mk));
    if (l15 == 0) {
#pragma unroll
        for (int mt = 0; mt < 2; ++mt)
#pragma unroll
            for (int i = 0; i < 4; ++i) wmax[mt * 16 + lq * 4 + i][w] = mxp[mt][i];
    }
    __syncthreads();

    float mx[2][4];
#pragma unroll
    for (int mt = 0; mt < 2; ++mt)
#pragma unroll
        for (int i = 0; i < 4; ++i) {
            const int r = mt * 16 + lq * 4 + i;
            f32x4 a = *(const f32x4*)&wmax[r][0];
            f32x4 b2 = *(const f32x4*)&wmax[r][4];
            mx[mt][i] = fmaxf(fmaxf(fmaxf(a[0], a[1]), fmaxf(a[2], a[3])),
                              fmaxf(fmaxf(b2[0], b2[1]), fmaxf(b2[2], b2[3])));
        }

    // ---- exp (unnormalized), write P, accumulate row sums ----
    float smp[2][4];
#pragma unroll
    for (int mt = 0; mt < 2; ++mt)
#pragma unroll
        for (int i = 0; i < 4; ++i) smp[mt][i] = 0.f;
#pragma unroll
    for (int nt = 0; nt < 8; ++nt) {
        const int col = w * 128 + nt * 16 + l15;
        const bool ok = col < vl;
#pragma unroll
        for (int mt = 0; mt < 2; ++mt)
#pragma unroll
            for (int i = 0; i < 4; ++i) {
                const int r = mt * 16 + lq * 4 + i;
                float p = 0.f;
                if (ok) {
                    p = __expf((sacc[mt][nt][i] - mx[mt][i]) * 0.125f);
                    smp[mt][i] += p;
                }
                P[r][col ^ (8 * (r & 7))] = f2bf(p);
            }
    }
#pragma unroll
    for (int mk = 1; mk < 16; mk <<= 1)
#pragma unroll
        for (int mt = 0; mt < 2; ++mt)
#pragma unroll
            for (int i = 0; i < 4; ++i) smp[mt][i] += __shfl_xor(smp[mt][i], mk);
    if (l15 == 0) {
#pragma unroll
        for (int mt = 0; mt < 2; ++mt)
#pragma unroll
            for (int i = 0; i < 4; ++i) wsum[mt * 16 + lq * 4 + i][w] = smp[mt][i];
    }
    __syncthreads();

    // ---- PV + X ----
    const int mt2 = w >> 2, dht = w & 3;
    f32x4 o0 = (f32x4){0.f, 0.f, 0.f, 0.f};
    f32x4 o1 = (f32x4){0.f, 0.f, 0.f, 0.f};
    f32x4 xa = (f32x4){0.f, 0.f, 0.f, 0.f};
#pragma unroll
    for (int kt2 = 0; kt2 < 2; ++kt2) {
        const float* qp = qm + ((size_t)b * SB + q0 + mt2 * 16 + l15) * MM + kt2 * 32 + 8 * lq;
        f32x4 qa = *(const f32x4*)qp;
        f32x4 qb2 = *(const f32x4*)(qp + 4);
        s16x8 at;
        at[0] = (short)f2bf(qa[0]);  at[1] = (short)f2bf(qa[1]);
        at[2] = (short)f2bf(qa[2]);  at[3] = (short)f2bf(qa[3]);
        at[4] = (short)f2bf(qb2[0]); at[5] = (short)f2bf(qb2[1]);
        at[6] = (short)f2bf(qb2[2]); at[7] = (short)f2bf(qb2[3]);
        s16x8 bu = *(const s16x8*)(U + ((size_t)bh * 64 + dht * 16 + l15) * 64 + kt2 * 32 + 8 * lq);
        xa = __builtin_amdgcn_mfma_f32_16x16x32_bf16(at, bu, xa, 0, 0, 0);
    }
    const int Rrow = mt2 * 16 + l15;
    const int sw = 8 * (Rrow & 7);
    const unsigned short* vbase = vht + ((size_t)bh * DHD + dht * 16 + l15) * SB;
#pragma unroll 8
    for (int kt = 0; kt < 32; kt += 2) {
        s16x8 pa0 = *(const s16x8*)(&P[Rrow][(kt * 32 + 8 * lq) ^ sw]);
        s16x8 pv0 = *(const s16x8*)(vbase + kt * 32 + 8 * lq);
        o0 = __builtin_amdgcn_mfma_f32_16x16x32_bf16(pa0, pv0, o0, 0, 0, 0);
        s16x8 pa1 = *(const s16x8*)(&P[Rrow][((kt + 1) * 32 + 8 * lq) ^ sw]);
        s16x8 pv1 = *(const s16x8*)(vbase + (kt + 1) * 32 + 8 * lq);
        o1 = __builtin_amdgcn_mfma_f32_16x16x32_bf16(pa1, pv1, o1, 0, 0, 0);
    }
#pragma unroll
    for (int i = 0; i < 4; ++i) {
        const int r = mt2 * 16 + lq * 4 + i;
        f32x4 s0 = *(const f32x4*)&wsum[r][0];
        f32x4 s1 = *(const f32x4*)&wsum[r][4];
        const float sum = s0[0] + s0[1] + s0[2] + s0[3] + s1[0] + s1[1] + s1[2] + s1[3];
        const float val = (o0[i] + o1[i]) / sum + xa[i] * cs;
        aout[((size_t)b * SB + q0 + r) * DD + h * DHD + dht * 16 + l15] = f2bf(val);
    }
}

// ---------------------------------------------------------------------------
extern "C" void kernel_launch(void* const* d_in, const int* in_sizes, int n_in,
                              void* d_out, int out_size, void* d_ws, size_t ws_size,
                              hipStream_t stream) {
    const float* q   = (const float*)d_in[0];
    const float* k   = (const float*)d_in[1];
    const float* v   = (const float*)d_in[2];
    const float* qm  = (const float*)d_in[3];
    const float* kvm = (const float*)d_in[4];
    const int* vl    = (const int*)d_in[5];
    const float* Wq  = (const float*)d_in[6];
    const float* Wk  = (const float*)d_in[7];
    const float* Wv  = (const float*)d_in[8];
    const float* Wo  = (const float*)d_in[9];
    const float* alpha = (const float*)d_in[10];

    char* ws = (char*)d_ws;
    unsigned short* Wt  = (unsigned short*)(ws);                        // 0..8MB
    unsigned short* qb  = (unsigned short*)(ws + ((size_t)8  << 20));   // 8..16MB
    unsigned short* kb  = (unsigned short*)(ws + ((size_t)16 << 20));   // 16..24MB
    unsigned short* vb  = (unsigned short*)(ws + ((size_t)24 << 20));   // 24..32MB
    unsigned short* qhp = (unsigned short*)(ws + ((size_t)32 << 20));   // 32..40MB
    unsigned short* khp = (unsigned short*)(ws + ((size_t)40 << 20));   // 40..48MB
    unsigned short* vht = (unsigned short*)(ws + ((size_t)48 << 20));   // 48..56MB
    unsigned short* U   = (unsigned short*)(ws + ((size_t)8  << 20));   // reuse qb (dead)
    float* csc          = (float*)(ws + ((size_t)9 << 20));             // 16B
    unsigned short* aout = (unsigned short*)(ws + ((size_t)16 << 20));  // reuse kb (dead)

    cvt_kernel<<<dim3(2048, 3, 1), 256, 0, stream>>>(q, k, v, qb, kb, vb);
    wtrans_kernel<<<dim3(32, 32, 4), dim3(32, 8, 1), 0, stream>>>(Wq, Wk, Wv, Wo, Wt);

    const dim3 gb(8, 32, 1);
    gemm_kernel<0><<<gb, 512, 0, stream>>>(qb, Wt + 0 * (1u << 20), qhp);
    gemm_kernel<0><<<gb, 512, 0, stream>>>(kb, Wt + 1 * (1u << 20), khp);
    gemm_kernel<1><<<gb, 512, 0, stream>>>(vb, Wt + 2 * (1u << 20), vht);

    uk_kernel<<<64, 256, 0, stream>>>(vht, kvm, U);
    gram_kernel<<<4, 256, 0, stream>>>(qm, kvm, alpha, csc);

    attn_kernel<<<dim3(32, 64, 1), 512, 0, stream>>>(qhp, khp, vht, U, csc, qm, vl, aout);
    gemm_kernel<2><<<gb, 512, 0, stream>>>(aout, Wt + 3 * (1u << 20), d_out);
}

// Round 5
// 249.976 us; speedup vs baseline: 1.6667x; 1.4019x over previous
//
#include <hip/hip_runtime.h>
#include <hip/hip_bf16.h>
#include <stdint.h>

// B=4, S=1024, D=1024, H=16, M=64, DH=64
#define SB 1024
#define DD 1024
#define NH 16
#define MM 64
#define DHD 64

typedef __attribute__((ext_vector_type(8))) short s16x8;
typedef __attribute__((ext_vector_type(4))) float f32x4;

__device__ __forceinline__ unsigned short f2bf(float f) {
    union { float f; unsigned int u; } v; v.f = f;
    unsigned int u = v.u;
    u += 0x7FFFu + ((u >> 16) & 1u);
    return (unsigned short)(u >> 16);
}

__device__ __forceinline__ void gload_lds16(const unsigned short* g, unsigned short* l) {
    __builtin_amdgcn_global_load_lds(
        (const __attribute__((address_space(1))) unsigned int*)g,
        (__attribute__((address_space(3))) unsigned int*)l, 16, 0, 0);
}

// ---------------------------------------------------------------------------
// q,k,v f32 -> bf16 copies. grid (2048, 3), block 256, 8 elems/thread.
// ---------------------------------------------------------------------------
__global__ __launch_bounds__(256) void cvt_kernel(const float* q, const float* k, const float* v,
                                                  unsigned short* qb, unsigned short* kb,
                                                  unsigned short* vb) {
    const int z = blockIdx.y;
    const float* src = (z == 0) ? q : (z == 1) ? k : v;
    unsigned short* dst = (z == 0) ? qb : (z == 1) ? kb : vb;
    const size_t base = ((size_t)blockIdx.x * 256 + threadIdx.x) * 8;
    f32x4 a = *(const f32x4*)(src + base);
    f32x4 b2 = *(const f32x4*)(src + base + 4);
    s16x8 t;
    t[0] = (short)f2bf(a[0]);  t[1] = (short)f2bf(a[1]);
    t[2] = (short)f2bf(a[2]);  t[3] = (short)f2bf(a[3]);
    t[4] = (short)f2bf(b2[0]); t[5] = (short)f2bf(b2[1]);
    t[6] = (short)f2bf(b2[2]); t[7] = (short)f2bf(b2[3]);
    *(s16x8*)(dst + base) = t;
}

// ---------------------------------------------------------------------------
// Transpose + convert the 4 weight matrices: Wt[n][k] = bf16(W[k][n])
// ---------------------------------------------------------------------------
__global__ __launch_bounds__(256) void wtrans_kernel(const float* W0, const float* W1,
                                                     const float* W2, const float* W3,
                                                     unsigned short* out) {
    const float* W = (blockIdx.z == 0) ? W0 : (blockIdx.z == 1) ? W1 : (blockIdx.z == 2) ? W2 : W3;
    unsigned short* Wt = out + (size_t)blockIdx.z * (size_t)DD * DD;
    __shared__ float tile[32][33];
    const int tx = threadIdx.x, ty = threadIdx.y;
    const int x0 = blockIdx.x * 32, y0 = blockIdx.y * 32;
#pragma unroll
    for (int j = 0; j < 4; ++j)
        tile[ty + 8 * j][tx] = W[(size_t)(y0 + ty + 8 * j) * DD + x0 + tx];
    __syncthreads();
#pragma unroll
    for (int j = 0; j < 4; ++j)
        Wt[(size_t)(x0 + ty + 8 * j) * DD + y0 + tx] = f2bf(tile[tx][ty + 8 * j]);
}

// ---------------------------------------------------------------------------
// GEMM: C[4096,1024] = A[4096,1024](bf16) @ Bt[n][k](bf16, transposed-stored)
// 128x128 tile, BK=64, 512 threads, global_load_lds(16) + XOR-swizzled source,
// 2-phase double-buffer. OMODE 0: head-split bf16; 1: v-transposed; 2: f32.
// ---------------------------------------------------------------------------
template <int OMODE>
__global__ __launch_bounds__(512) void gemm_kernel(const unsigned short* A, const unsigned short* Bt,
                                                   void* outp) {
    __shared__ unsigned short lds[2][2][128][64];
    const int tid = threadIdx.x, l = tid & 63, w = tid >> 6;
    const int l15 = l & 15, lq = l >> 4;
    const int m0b = blockIdx.y * 128, n0b = blockIdx.x * 128;
    const int wm = (w >> 1) * 32, wn = (w & 1) * 64;
    const int ric = l >> 3;
    const int gsrc = (l & 7) ^ (ric & 7);

    f32x4 acc[2][4];
#pragma unroll
    for (int i = 0; i < 2; ++i)
#pragma unroll
        for (int j = 0; j < 4; ++j) acc[i][j] = (f32x4){0.f, 0.f, 0.f, 0.f};

    auto STAGE = [&](int bb, int kt) {
        const int k0 = kt * 64;
#pragma unroll
        for (int j = 0; j < 2; ++j) {
            const int chunk = w * 2 + j;
            const int r = chunk * 8 + ric;
            gload_lds16(A + (size_t)(m0b + r) * DD + k0 + gsrc * 8, &lds[bb][0][chunk * 8][0]);
            gload_lds16(Bt + (size_t)(n0b + r) * DD + k0 + gsrc * 8, &lds[bb][1][chunk * 8][0]);
        }
    };

    STAGE(0, 0);
    __syncthreads();
    int cur = 0;
    for (int kt = 0; kt < 16; ++kt) {
        if (kt < 15) STAGE(cur ^ 1, kt + 1);
#pragma unroll
        for (int kt2 = 0; kt2 < 2; ++kt2) {
            s16x8 af[2], bf[4];
#pragma unroll
            for (int mi = 0; mi < 2; ++mi) {
                const int R = wm + mi * 16 + l15;
                af[mi] = *(const s16x8*)(&lds[cur][0][R][((kt2 * 4 + lq) ^ (R & 7)) * 8]);
            }
#pragma unroll
            for (int ni = 0; ni < 4; ++ni) {
                const int R = wn + ni * 16 + l15;
                bf[ni] = *(const s16x8*)(&lds[cur][1][R][((kt2 * 4 + lq) ^ (R & 7)) * 8]);
            }
#pragma unroll
            for (int mi = 0; mi < 2; ++mi)
#pragma unroll
                for (int ni = 0; ni < 4; ++ni)
                    acc[mi][ni] = __builtin_amdgcn_mfma_f32_16x16x32_bf16(af[mi], bf[ni],
                                                                          acc[mi][ni], 0, 0, 0);
        }
        __syncthreads();
        cur ^= 1;
    }

#pragma unroll
    for (int mi = 0; mi < 2; ++mi)
#pragma unroll
        for (int ni = 0; ni < 4; ++ni)
#pragma unroll
            for (int i = 0; i < 4; ++i) {
                const int r = m0b + wm + mi * 16 + lq * 4 + i;
                const int c = n0b + wn + ni * 16 + l15;
                const float vv = acc[mi][ni][i];
                if (OMODE == 2) {
                    ((float*)outp)[(size_t)r * DD + c] = vv;
                } else {
                    const int b = r >> 10, s = r & 1023;
                    const int hh = c >> 6, dh = c & 63;
                    if (OMODE == 0)
                        ((unsigned short*)outp)[((size_t)((b * NH + hh) * SB + s)) * DHD + dh] = f2bf(vv);
                    else
                        ((unsigned short*)outp)[((size_t)((b * NH + hh) * DHD + dh)) * SB + s] = f2bf(vv);
                }
            }
}

// ---------------------------------------------------------------------------
// U[bh] = vht[bh] (64dh x 1024s) @ kvm[b] (1024s x 64m) -> bf16 [dh][m]
// ---------------------------------------------------------------------------
__global__ __launch_bounds__(256) void uk_kernel(const unsigned short* vht, const float* kvm,
                                                 unsigned short* U) {
    const int bh = blockIdx.x, b = bh >> 4;
    const int tid = threadIdx.x, l = tid & 63, w = tid >> 6;
    const int l15 = l & 15, lq = l >> 4;
    __shared__ float part[4][64][64];

    f32x4 acc[4][4];
#pragma unroll
    for (int i = 0; i < 4; ++i)
#pragma unroll
        for (int j = 0; j < 4; ++j) acc[i][j] = (f32x4){0.f, 0.f, 0.f, 0.f};

    for (int kt2 = 0; kt2 < 8; ++kt2) {
        const int sbase = w * 256 + kt2 * 32 + 8 * lq;
        s16x8 av[4], bk[4];
#pragma unroll
        for (int t = 0; t < 4; ++t)
            av[t] = *(const s16x8*)(vht + ((size_t)bh * DHD + t * 16 + l15) * SB + sbase);
#pragma unroll
        for (int t = 0; t < 4; ++t) {
            s16x8 tmp;
#pragma unroll
            for (int j = 0; j < 8; ++j)
                tmp[j] = (short)f2bf(kvm[((size_t)b * SB + sbase + j) * MM + t * 16 + l15]);
            bk[t] = tmp;
        }
#pragma unroll
        for (int at = 0; at < 4; ++at)
#pragma unroll
            for (int bt = 0; bt < 4; ++bt)
                acc[at][bt] = __builtin_amdgcn_mfma_f32_16x16x32_bf16(av[at], bk[bt],
                                                                      acc[at][bt], 0, 0, 0);
    }
#pragma unroll
    for (int at = 0; at < 4; ++at)
#pragma unroll
        for (int bt = 0; bt < 4; ++bt)
#pragma unroll
            for (int i = 0; i < 4; ++i)
                part[w][at * 16 + lq * 4 + i][bt * 16 + l15] = acc[at][bt][i];
    __syncthreads();
    for (int e = tid * 16; e < tid * 16 + 16; ++e) {
        const int r = e >> 6, c = e & 63;
        U[(size_t)bh * 4096 + e] =
            f2bf(part[0][r][c] + part[1][r][c] + part[2][r][c] + part[3][r][c]);
    }
}

// ---------------------------------------------------------------------------
// cscale[b] = alpha / (sqrt(alpha^2 * sum(Gq o Gk)) + 1e-5)
// ---------------------------------------------------------------------------
__global__ __launch_bounds__(256) void gram_kernel(const float* qm, const float* kvm,
                                                   const float* alpha_p, float* cscale) {
    const int b = blockIdx.x;
    const int tid = threadIdx.x, l = tid & 63, w = tid >> 6;
    const int l15 = l & 15, lq = l >> 4;
    __shared__ float part[4][64][64];
    __shared__ float gq[64][64];
    __shared__ float red[4];

    f32x4 acc[4][4];
#pragma unroll
    for (int i = 0; i < 4; ++i)
#pragma unroll
        for (int j = 0; j < 4; ++j) acc[i][j] = (f32x4){0.f, 0.f, 0.f, 0.f};
    for (int kt2 = 0; kt2 < 8; ++kt2) {
        const int sbase = w * 256 + kt2 * 32 + 8 * lq;
        s16x8 fq[4];
#pragma unroll
        for (int t = 0; t < 4; ++t) {
            s16x8 tmp;
#pragma unroll
            for (int j = 0; j < 8; ++j)
                tmp[j] = (short)f2bf(qm[((size_t)b * SB + sbase + j) * MM + t * 16 + l15]);
            fq[t] = tmp;
        }
#pragma unroll
        for (int at = 0; at < 4; ++at)
#pragma unroll
            for (int bt = 0; bt < 4; ++bt)
                acc[at][bt] = __builtin_amdgcn_mfma_f32_16x16x32_bf16(fq[at], fq[bt],
                                                                     acc[at][bt], 0, 0, 0);
    }
#pragma unroll
    for (int at = 0; at < 4; ++at)
#pragma unroll
        for (int bt = 0; bt < 4; ++bt)
#pragma unroll
            for (int i = 0; i < 4; ++i)
                part[w][at * 16 + lq * 4 + i][bt * 16 + l15] = acc[at][bt][i];
    __syncthreads();
    for (int e = tid * 16; e < tid * 16 + 16; ++e) {
        const int r = e >> 6, c = e & 63;
        gq[r][c] = part[0][r][c] + part[1][r][c] + part[2][r][c] + part[3][r][c];
    }
    __syncthreads();

#pragma unroll
    for (int i = 0; i < 4; ++i)
#pragma unroll
        for (int j = 0; j < 4; ++j) acc[i][j] = (f32x4){0.f, 0.f, 0.f, 0.f};
    for (int kt2 = 0; kt2 < 8; ++kt2) {
        const int sbase = w * 256 + kt2 * 32 + 8 * lq;
        s16x8 fk[4];
#pragma unroll
        for (int t = 0; t < 4; ++t) {
            s16x8 tmp;
#pragma unroll
            for (int j = 0; j < 8; ++j)
                tmp[j] = (short)f2bf(kvm[((size_t)b * SB + sbase + j) * MM + t * 16 + l15]);
            fk[t] = tmp;
        }
#pragma unroll
        for (int at = 0; at < 4; ++at)
#pragma unroll
            for (int bt = 0; bt < 4; ++bt)
                acc[at][bt] = __builtin_amdgcn_mfma_f32_16x16x32_bf16(fk[at], fk[bt],
                                                                     acc[at][bt], 0, 0, 0);
    }
#pragma unroll
    for (int at = 0; at < 4; ++at)
#pragma unroll
        for (int bt = 0; bt < 4; ++bt)
#pragma unroll
            for (int i = 0; i < 4; ++i)
                part[w][at * 16 + lq * 4 + i][bt * 16 + l15] = acc[at][bt][i];
    __syncthreads();
    float ss = 0.f;
    for (int e = tid * 16; e < tid * 16 + 16; ++e) {
        const int r = e >> 6, c = e & 63;
        const float gk = part[0][r][c] + part[1][r][c] + part[2][r][c] + part[3][r][c];
        ss += gk * gq[r][c];
    }
#pragma unroll
    for (int mk = 1; mk < 64; mk <<= 1) ss += __shfl_xor(ss, mk);
    if (l == 0) red[w] = ss;
    __syncthreads();
    if (tid == 0) {
        const float S = red[0] + red[1] + red[2] + red[3];
        const float a = alpha_p[0];
        cscale[b] = a / (sqrtf(a * a * S) + 1e-5f);
    }
}

// ---------------------------------------------------------------------------
// Flash attention: grid 512 = 64 bh x 8 q-splits (XCD-swizzled: wg&7 = XCD,
// all q-splits of a bh on one XCD). 8 waves x 16 q-rows. kv-tiles of 64 keys
// double-buffered in LDS via global_load_lds (swizzled source); online
// softmax in registers; P through per-wave swizzled LDS; tiles >= vl skipped.
// Epilogue adds X = qm @ U^T * cscale and writes aout.
// ---------------------------------------------------------------------------
__global__ __launch_bounds__(512, 4) void attn_kernel(const unsigned short* qh, const unsigned short* kh,
                                                      const unsigned short* vht, const unsigned short* U,
                                                      const float* cscale, const float* qm,
                                                      const int* valid_lens, unsigned short* aout) {
    const int wg = blockIdx.x;
    const int xcd = wg & 7, ii = wg >> 3;
    const int bh = (ii >> 3) * 8 + xcd;          // same-bh blocks -> same XCD
    const int q0 = (ii & 7) * 128;
    const int b = bh >> 4, h = bh & 15;
    const int tid = threadIdx.x, l = tid & 63, w = tid >> 6;
    const int l15 = l & 15, lq = l >> 4;
    const int vl = valid_lens[b];
    const float cs = cscale[b];
    const int ntile = (vl + 63) >> 6;

    __shared__ unsigned short Kt[2][64][64];   // [buf][key][dh], granule^=(key&7)
    __shared__ unsigned short Vt[2][64][64];   // [buf][dh][key], granule^=(dh&7)
    __shared__ unsigned short Pl[8][16][64];   // per-wave P, col^=(8*(row&7))

    const int sr = tid >> 3;                   // staging row 0..63
    const int sgs = (tid & 7) ^ (sr & 7);      // pre-swizzled source granule
    const unsigned short* khb = kh + (size_t)bh * SB * DHD;
    const unsigned short* vhb = vht + (size_t)bh * DHD * SB;

    auto STAGE = [&](int bb, int t) {
        const int kv0 = t << 6;
        gload_lds16(khb + (size_t)(kv0 + sr) * DHD + sgs * 8, &Kt[bb][w * 8][0]);
        gload_lds16(vhb + (size_t)sr * SB + kv0 + sgs * 8, &Vt[bb][w * 8][0]);
    };

    // Q fragments for this wave's 16 rows
    s16x8 aq[2];
#pragma unroll
    for (int kt = 0; kt < 2; ++kt)
        aq[kt] = *(const s16x8*)(qh + ((size_t)bh * SB + q0 + w * 16 + l15) * DHD + kt * 32 + 8 * lq);

    float m_[4], l_[4];
    f32x4 oacc[4];
#pragma unroll
    for (int i = 0; i < 4; ++i) { m_[i] = -3.0e38f; l_[i] = 0.f; }
#pragma unroll
    for (int nd = 0; nd < 4; ++nd) oacc[nd] = (f32x4){0.f, 0.f, 0.f, 0.f};

    STAGE(0, 0);
    __syncthreads();
    int cur = 0;
    for (int t = 0; t < ntile; ++t) {
        if (t + 1 < ntile) STAGE(cur ^ 1, t + 1);
        const int kv0 = t << 6;
        const bool bdry = (kv0 + 64 > vl);

        // ---- QK^T (B-frags from swizzled Kt) ----
        f32x4 sc[4];
#pragma unroll
        for (int nt = 0; nt < 4; ++nt) {
            const int r = nt * 16 + l15;
            s16x8 b0 = *(const s16x8*)(&Kt[cur][r][((lq) ^ (r & 7)) * 8]);
            s16x8 b1 = *(const s16x8*)(&Kt[cur][r][((4 + lq) ^ (r & 7)) * 8]);
            f32x4 z = (f32x4){0.f, 0.f, 0.f, 0.f};
            z = __builtin_amdgcn_mfma_f32_16x16x32_bf16(aq[0], b0, z, 0, 0, 0);
            sc[nt] = __builtin_amdgcn_mfma_f32_16x16x32_bf16(aq[1], b1, z, 0, 0, 0);
        }

        // ---- tile row-max (raw units) ----
        float tm[4] = {-3.0e38f, -3.0e38f, -3.0e38f, -3.0e38f};
#pragma unroll
        for (int nt = 0; nt < 4; ++nt) {
            const bool ok = !bdry || (kv0 + nt * 16 + l15 < vl);
            if (ok) {
#pragma unroll
                for (int i = 0; i < 4; ++i) tm[i] = fmaxf(tm[i], sc[nt][i]);
            }
        }
#pragma unroll
        for (int mk = 1; mk < 16; mk <<= 1)
#pragma unroll
            for (int i = 0; i < 4; ++i) tm[i] = fmaxf(tm[i], __shfl_xor(tm[i], mk));

        // ---- online rescale ----
#pragma unroll
        for (int i = 0; i < 4; ++i) {
            const float mn = fmaxf(m_[i], tm[i]);
            const float rs = __expf((m_[i] - mn) * 0.125f);
            m_[i] = mn;
            l_[i] *= rs;
#pragma unroll
            for (int nd = 0; nd < 4; ++nd) oacc[nd][i] *= rs;
        }

        // ---- p = exp, accumulate l (lane-partial), write P (swizzled) ----
#pragma unroll
        for (int nt = 0; nt < 4; ++nt) {
            const bool ok = !bdry || (kv0 + nt * 16 + l15 < vl);
#pragma unroll
            for (int i = 0; i < 4; ++i) {
                const float p = ok ? __expf((sc[nt][i] - m_[i]) * 0.125f) : 0.f;
                l_[i] += p;
                const int pr = lq * 4 + i;
                Pl[w][pr][(nt * 16 + l15) ^ (8 * (pr & 7))] = f2bf(p);
            }
        }

        // ---- PV accumulate ----
#pragma unroll
        for (int kt = 0; kt < 2; ++kt) {
            s16x8 pa = *(const s16x8*)(&Pl[w][l15][((kt * 4 + lq) ^ (l15 & 7)) * 8]);
#pragma unroll
            for (int nd = 0; nd < 4; ++nd) {
                const int r = nd * 16 + l15;
                s16x8 vb = *(const s16x8*)(&Vt[cur][r][((kt * 4 + lq) ^ (r & 7)) * 8]);
                oacc[nd] = __builtin_amdgcn_mfma_f32_16x16x32_bf16(pa, vb, oacc[nd], 0, 0, 0);
            }
        }
        __syncthreads();
        cur ^= 1;
    }

    // ---- FIX (R4 bug): reduce lane-partial softmax denominators across the
    // 16 lanes of each row group (each lane summed only cols ≡ l15 mod 16).
#pragma unroll
    for (int mk = 1; mk < 16; mk <<= 1)
#pragma unroll
        for (int i = 0; i < 4; ++i) l_[i] += __shfl_xor(l_[i], mk);

    // ---- epilogue: X = qm @ U^T, out = O/l + X*cs ----
    s16x8 xa[2];
#pragma unroll
    for (int kt2 = 0; kt2 < 2; ++kt2) {
        const float* qp = qm + ((size_t)b * SB + q0 + w * 16 + l15) * MM + kt2 * 32 + 8 * lq;
        f32x4 qa = *(const f32x4*)qp;
        f32x4 qb2 = *(const f32x4*)(qp + 4);
        s16x8 at;
        at[0] = (short)f2bf(qa[0]);  at[1] = (short)f2bf(qa[1]);
        at[2] = (short)f2bf(qa[2]);  at[3] = (short)f2bf(qa[3]);
        at[4] = (short)f2bf(qb2[0]); at[5] = (short)f2bf(qb2[1]);
        at[6] = (short)f2bf(qb2[2]); at[7] = (short)f2bf(qb2[3]);
        xa[kt2] = at;
    }
    float rinv[4];
#pragma unroll
    for (int i = 0; i < 4; ++i) rinv[i] = 1.f / l_[i];
#pragma unroll
    for (int nd = 0; nd < 4; ++nd) {
        f32x4 xacc = (f32x4){0.f, 0.f, 0.f, 0.f};
#pragma unroll
        for (int kt2 = 0; kt2 < 2; ++kt2) {
            s16x8 bu = *(const s16x8*)(U + ((size_t)bh * 64 + nd * 16 + l15) * 64 + kt2 * 32 + 8 * lq);
            xacc = __builtin_amdgcn_mfma_f32_16x16x32_bf16(xa[kt2], bu, xacc, 0, 0, 0);
        }
#pragma unroll
        for (int i = 0; i < 4; ++i) {
            const int row = q0 + w * 16 + lq * 4 + i;
            const float val = oacc[nd][i] * rinv[i] + xacc[i] * cs;
            aout[((size_t)b * SB + row) * DD + h * DHD + nd * 16 + l15] = f2bf(val);
        }
    }
}

// ---------------------------------------------------------------------------
extern "C" void kernel_launch(void* const* d_in, const int* in_sizes, int n_in,
                              void* d_out, int out_size, void* d_ws, size_t ws_size,
                              hipStream_t stream) {
    const float* q   = (const float*)d_in[0];
    const float* k   = (const float*)d_in[1];
    const float* v   = (const float*)d_in[2];
    const float* qm  = (const float*)d_in[3];
    const float* kvm = (const float*)d_in[4];
    const int* vl    = (const int*)d_in[5];
    const float* Wq  = (const float*)d_in[6];
    const float* Wk  = (const float*)d_in[7];
    const float* Wv  = (const float*)d_in[8];
    const float* Wo  = (const float*)d_in[9];
    const float* alpha = (const float*)d_in[10];

    char* ws = (char*)d_ws;
    unsigned short* Wt  = (unsigned short*)(ws);                        // 0..8MB
    unsigned short* qb  = (unsigned short*)(ws + ((size_t)8  << 20));   // 8..16MB
    unsigned short* kb  = (unsigned short*)(ws + ((size_t)16 << 20));   // 16..24MB
    unsigned short* vb  = (unsigned short*)(ws + ((size_t)24 << 20));   // 24..32MB
    unsigned short* qhp = (unsigned short*)(ws + ((size_t)32 << 20));   // 32..40MB
    unsigned short* khp = (unsigned short*)(ws + ((size_t)40 << 20));   // 40..48MB
    unsigned short* vht = (unsigned short*)(ws + ((size_t)48 << 20));   // 48..56MB
    unsigned short* U   = (unsigned short*)(ws + ((size_t)8  << 20));   // reuse qb (dead)
    float* csc          = (float*)(ws + ((size_t)9 << 20));             // 16B
    unsigned short* aout = (unsigned short*)(ws + ((size_t)16 << 20));  // reuse kb (dead)

    cvt_kernel<<<dim3(2048, 3, 1), 256, 0, stream>>>(q, k, v, qb, kb, vb);
    wtrans_kernel<<<dim3(32, 32, 4), dim3(32, 8, 1), 0, stream>>>(Wq, Wk, Wv, Wo, Wt);

    const dim3 gb(8, 32, 1);
    gemm_kernel<0><<<gb, 512, 0, stream>>>(qb, Wt + 0 * (1u << 20), qhp);
    gemm_kernel<0><<<gb, 512, 0, stream>>>(kb, Wt + 1 * (1u << 20), khp);
    gemm_kernel<1><<<gb, 512, 0, stream>>>(vb, Wt + 2 * (1u << 20), vht);

    uk_kernel<<<64, 256, 0, stream>>>(vht, kvm, U);
    gram_kernel<<<4, 256, 0, stream>>>(qm, kvm, alpha, csc);

    attn_kernel<<<512, 512, 0, stream>>>(qhp, khp, vht, U, csc, qm, vl, aout);
    gemm_kernel<2><<<gb, 512, 0, stream>>>(aout, Wt + 3 * (1u << 20), d_out);
}

// Round 6
// 238.301 us; speedup vs baseline: 1.7483x; 1.0490x over previous
//
#include <hip/hip_runtime.h>
#include <hip/hip_bf16.h>
#include <stdint.h>

// B=4, S=1024, D=1024, H=16, M=64, DH=64
#define SB 1024
#define DD 1024
#define NH 16
#define MM 64
#define DHD 64

typedef __attribute__((ext_vector_type(8))) short s16x8;
typedef __attribute__((ext_vector_type(4))) float f32x4;

__device__ __forceinline__ unsigned short f2bf(float f) {
    union { float f; unsigned int u; } v; v.f = f;
    unsigned int u = v.u;
    u += 0x7FFFu + ((u >> 16) & 1u);
    return (unsigned short)(u >> 16);
}

__device__ __forceinline__ void gload_lds16(const unsigned short* g, unsigned short* l) {
    __builtin_amdgcn_global_load_lds(
        (const __attribute__((address_space(1))) unsigned int*)g,
        (__attribute__((address_space(3))) unsigned int*)l, 16, 0, 0);
}

// ---------------------------------------------------------------------------
// q,k,v f32 -> bf16 copies. grid (2048, 3), block 256, 8 elems/thread.
// ---------------------------------------------------------------------------
__global__ __launch_bounds__(256) void cvt_kernel(const float* q, const float* k, const float* v,
                                                  unsigned short* qb, unsigned short* kb,
                                                  unsigned short* vb) {
    const int z = blockIdx.y;
    const float* src = (z == 0) ? q : (z == 1) ? k : v;
    unsigned short* dst = (z == 0) ? qb : (z == 1) ? kb : vb;
    const size_t base = ((size_t)blockIdx.x * 256 + threadIdx.x) * 8;
    f32x4 a = *(const f32x4*)(src + base);
    f32x4 b2 = *(const f32x4*)(src + base + 4);
    s16x8 t;
    t[0] = (short)f2bf(a[0]);  t[1] = (short)f2bf(a[1]);
    t[2] = (short)f2bf(a[2]);  t[3] = (short)f2bf(a[3]);
    t[4] = (short)f2bf(b2[0]); t[5] = (short)f2bf(b2[1]);
    t[6] = (short)f2bf(b2[2]); t[7] = (short)f2bf(b2[3]);
    *(s16x8*)(dst + base) = t;
}

// ---------------------------------------------------------------------------
// Transpose + convert the 4 weight matrices: Wt[n][k] = bf16(W[k][n])
// ---------------------------------------------------------------------------
__global__ __launch_bounds__(256) void wtrans_kernel(const float* W0, const float* W1,
                                                     const float* W2, const float* W3,
                                                     unsigned short* out) {
    const float* W = (blockIdx.z == 0) ? W0 : (blockIdx.z == 1) ? W1 : (blockIdx.z == 2) ? W2 : W3;
    unsigned short* Wt = out + (size_t)blockIdx.z * (size_t)DD * DD;
    __shared__ float tile[32][33];
    const int tx = threadIdx.x, ty = threadIdx.y;
    const int x0 = blockIdx.x * 32, y0 = blockIdx.y * 32;
#pragma unroll
    for (int j = 0; j < 4; ++j)
        tile[ty + 8 * j][tx] = W[(size_t)(y0 + ty + 8 * j) * DD + x0 + tx];
    __syncthreads();
#pragma unroll
    for (int j = 0; j < 4; ++j)
        Wt[(size_t)(x0 + ty + 8 * j) * DD + y0 + tx] = f2bf(tile[tx][ty + 8 * j]);
}

// ---------------------------------------------------------------------------
// GEMM body: C[128x128 tile at (m0b,n0b)] = A @ Bt^T, bf16 MFMA, BK=64,
// 512 threads, gload_lds(16) + XOR-swizzled source, double-buffered.
// OMODE 0: head-split bf16; 1: v-transposed bf16; 2: f32 flat.
// ---------------------------------------------------------------------------
template <int OMODE>
__device__ __forceinline__ void gemm_body(const unsigned short* A, const unsigned short* Bt,
                                          void* outp, int m0b, int n0b) {
    __shared__ unsigned short lds[2][2][128][64];
    const int tid = threadIdx.x, l = tid & 63, w = tid >> 6;
    const int l15 = l & 15, lq = l >> 4;
    const int wm = (w >> 1) * 32, wn = (w & 1) * 64;
    const int ric = l >> 3;
    const int gsrc = (l & 7) ^ (ric & 7);

    f32x4 acc[2][4];
#pragma unroll
    for (int i = 0; i < 2; ++i)
#pragma unroll
        for (int j = 0; j < 4; ++j) acc[i][j] = (f32x4){0.f, 0.f, 0.f, 0.f};

    auto STAGE = [&](int bb, int kt) {
        const int k0 = kt * 64;
#pragma unroll
        for (int j = 0; j < 2; ++j) {
            const int chunk = w * 2 + j;
            const int r = chunk * 8 + ric;
            gload_lds16(A + (size_t)(m0b + r) * DD + k0 + gsrc * 8, &lds[bb][0][chunk * 8][0]);
            gload_lds16(Bt + (size_t)(n0b + r) * DD + k0 + gsrc * 8, &lds[bb][1][chunk * 8][0]);
        }
    };

    STAGE(0, 0);
    __syncthreads();
    int cur = 0;
    for (int kt = 0; kt < 16; ++kt) {
        if (kt < 15) STAGE(cur ^ 1, kt + 1);
#pragma unroll
        for (int kt2 = 0; kt2 < 2; ++kt2) {
            s16x8 af[2], bf[4];
#pragma unroll
            for (int mi = 0; mi < 2; ++mi) {
                const int R = wm + mi * 16 + l15;
                af[mi] = *(const s16x8*)(&lds[cur][0][R][((kt2 * 4 + lq) ^ (R & 7)) * 8]);
            }
#pragma unroll
            for (int ni = 0; ni < 4; ++ni) {
                const int R = wn + ni * 16 + l15;
                bf[ni] = *(const s16x8*)(&lds[cur][1][R][((kt2 * 4 + lq) ^ (R & 7)) * 8]);
            }
#pragma unroll
            for (int mi = 0; mi < 2; ++mi)
#pragma unroll
                for (int ni = 0; ni < 4; ++ni)
                    acc[mi][ni] = __builtin_amdgcn_mfma_f32_16x16x32_bf16(af[mi], bf[ni],
                                                                          acc[mi][ni], 0, 0, 0);
        }
        __syncthreads();
        cur ^= 1;
    }

#pragma unroll
    for (int mi = 0; mi < 2; ++mi)
#pragma unroll
        for (int ni = 0; ni < 4; ++ni)
#pragma unroll
            for (int i = 0; i < 4; ++i) {
                const int r = m0b + wm + mi * 16 + lq * 4 + i;
                const int c = n0b + wn + ni * 16 + l15;
                const float vv = acc[mi][ni][i];
                if (OMODE == 2) {
                    ((float*)outp)[(size_t)r * DD + c] = vv;
                } else {
                    const int b = r >> 10, s = r & 1023;
                    const int hh = c >> 6, dh = c & 63;
                    if (OMODE == 0)
                        ((unsigned short*)outp)[((size_t)((b * NH + hh) * SB + s)) * DHD + dh] = f2bf(vv);
                    else
                        ((unsigned short*)outp)[((size_t)((b * NH + hh) * DHD + dh)) * SB + s] = f2bf(vv);
                }
            }
}

// XCD-aware decode: 256 blocks/tensor; 4 consecutive A-panels + whole B per XCD
// -> per-XCD L2 working set ~3MB (fits 4MB).
__device__ __forceinline__ void xcd_decode(int i, int& m0b, int& n0b) {
    const int xcd = i & 7, idx = i >> 3;
    m0b = (xcd * 4 + (idx >> 3)) * 128;
    n0b = (idx & 7) * 128;
}

// Fused QKV projections: grid 768 = 3 tensors x 256 tiles.
__global__ __launch_bounds__(512) void gemm_qkv_kernel(const unsigned short* qb,
                                                       const unsigned short* kb,
                                                       const unsigned short* vb,
                                                       const unsigned short* Wt,
                                                       unsigned short* qhp, unsigned short* khp,
                                                       unsigned short* vht) {
    const int wg = blockIdx.x;
    const int t = wg >> 8, i = wg & 255;
    int m0b, n0b;
    xcd_decode(i, m0b, n0b);
    const unsigned short* Bt = Wt + (size_t)t * DD * DD;
    if (t == 0)      gemm_body<0>(qb, Bt, qhp, m0b, n0b);
    else if (t == 1) gemm_body<0>(kb, Bt, khp, m0b, n0b);
    else             gemm_body<1>(vb, Bt, vht, m0b, n0b);
}

// Output projection: grid 256.
__global__ __launch_bounds__(512) void gemm_o_kernel(const unsigned short* aout,
                                                     const unsigned short* WtO, float* out) {
    int m0b, n0b;
    xcd_decode(blockIdx.x, m0b, n0b);
    gemm_body<2>(aout, WtO, out, m0b, n0b);
}

// ---------------------------------------------------------------------------
// U[bh] = vht[bh] (64dh x 1024s) @ kvm[b] (1024s x 64m) -> bf16 [dh][m]
// ---------------------------------------------------------------------------
__global__ __launch_bounds__(256) void uk_kernel(const unsigned short* vht, const float* kvm,
                                                 unsigned short* U) {
    const int bh = blockIdx.x, b = bh >> 4;
    const int tid = threadIdx.x, l = tid & 63, w = tid >> 6;
    const int l15 = l & 15, lq = l >> 4;
    __shared__ float part[4][64][64];

    f32x4 acc[4][4];
#pragma unroll
    for (int i = 0; i < 4; ++i)
#pragma unroll
        for (int j = 0; j < 4; ++j) acc[i][j] = (f32x4){0.f, 0.f, 0.f, 0.f};

    for (int kt2 = 0; kt2 < 8; ++kt2) {
        const int sbase = w * 256 + kt2 * 32 + 8 * lq;
        s16x8 av[4], bk[4];
#pragma unroll
        for (int t = 0; t < 4; ++t)
            av[t] = *(const s16x8*)(vht + ((size_t)bh * DHD + t * 16 + l15) * SB + sbase);
#pragma unroll
        for (int t = 0; t < 4; ++t) {
            s16x8 tmp;
#pragma unroll
            for (int j = 0; j < 8; ++j)
                tmp[j] = (short)f2bf(kvm[((size_t)b * SB + sbase + j) * MM + t * 16 + l15]);
            bk[t] = tmp;
        }
#pragma unroll
        for (int at = 0; at < 4; ++at)
#pragma unroll
            for (int bt = 0; bt < 4; ++bt)
                acc[at][bt] = __builtin_amdgcn_mfma_f32_16x16x32_bf16(av[at], bk[bt],
                                                                      acc[at][bt], 0, 0, 0);
    }
#pragma unroll
    for (int at = 0; at < 4; ++at)
#pragma unroll
        for (int bt = 0; bt < 4; ++bt)
#pragma unroll
            for (int i = 0; i < 4; ++i)
                part[w][at * 16 + lq * 4 + i][bt * 16 + l15] = acc[at][bt][i];
    __syncthreads();
    for (int e = tid * 16; e < tid * 16 + 16; ++e) {
        const int r = e >> 6, c = e & 63;
        U[(size_t)bh * 4096 + e] =
            f2bf(part[0][r][c] + part[1][r][c] + part[2][r][c] + part[3][r][c]);
    }
}

// ---------------------------------------------------------------------------
// cscale[b] = alpha / (sqrt(alpha^2 * sum(Gq o Gk)) + 1e-5)
// ---------------------------------------------------------------------------
__global__ __launch_bounds__(256) void gram_kernel(const float* qm, const float* kvm,
                                                   const float* alpha_p, float* cscale) {
    const int b = blockIdx.x;
    const int tid = threadIdx.x, l = tid & 63, w = tid >> 6;
    const int l15 = l & 15, lq = l >> 4;
    __shared__ float part[4][64][64];
    __shared__ float gq[64][64];
    __shared__ float red[4];

    f32x4 acc[4][4];
#pragma unroll
    for (int i = 0; i < 4; ++i)
#pragma unroll
        for (int j = 0; j < 4; ++j) acc[i][j] = (f32x4){0.f, 0.f, 0.f, 0.f};
    for (int kt2 = 0; kt2 < 8; ++kt2) {
        const int sbase = w * 256 + kt2 * 32 + 8 * lq;
        s16x8 fq[4];
#pragma unroll
        for (int t = 0; t < 4; ++t) {
            s16x8 tmp;
#pragma unroll
            for (int j = 0; j < 8; ++j)
                tmp[j] = (short)f2bf(qm[((size_t)b * SB + sbase + j) * MM + t * 16 + l15]);
            fq[t] = tmp;
        }
#pragma unroll
        for (int at = 0; at < 4; ++at)
#pragma unroll
            for (int bt = 0; bt < 4; ++bt)
                acc[at][bt] = __builtin_amdgcn_mfma_f32_16x16x32_bf16(fq[at], fq[bt],
                                                                     acc[at][bt], 0, 0, 0);
    }
#pragma unroll
    for (int at = 0; at < 4; ++at)
#pragma unroll
        for (int bt = 0; bt < 4; ++bt)
#pragma unroll
            for (int i = 0; i < 4; ++i)
                part[w][at * 16 + lq * 4 + i][bt * 16 + l15] = acc[at][bt][i];
    __syncthreads();
    for (int e = tid * 16; e < tid * 16 + 16; ++e) {
        const int r = e >> 6, c = e & 63;
        gq[r][c] = part[0][r][c] + part[1][r][c] + part[2][r][c] + part[3][r][c];
    }
    __syncthreads();

#pragma unroll
    for (int i = 0; i < 4; ++i)
#pragma unroll
        for (int j = 0; j < 4; ++j) acc[i][j] = (f32x4){0.f, 0.f, 0.f, 0.f};
    for (int kt2 = 0; kt2 < 8; ++kt2) {
        const int sbase = w * 256 + kt2 * 32 + 8 * lq;
        s16x8 fk[4];
#pragma unroll
        for (int t = 0; t < 4; ++t) {
            s16x8 tmp;
#pragma unroll
            for (int j = 0; j < 8; ++j)
                tmp[j] = (short)f2bf(kvm[((size_t)b * SB + sbase + j) * MM + t * 16 + l15]);
            fk[t] = tmp;
        }
#pragma unroll
        for (int at = 0; at < 4; ++at)
#pragma unroll
            for (int bt = 0; bt < 4; ++bt)
                acc[at][bt] = __builtin_amdgcn_mfma_f32_16x16x32_bf16(fk[at], fk[bt],
                                                                     acc[at][bt], 0, 0, 0);
    }
#pragma unroll
    for (int at = 0; at < 4; ++at)
#pragma unroll
        for (int bt = 0; bt < 4; ++bt)
#pragma unroll
            for (int i = 0; i < 4; ++i)
                part[w][at * 16 + lq * 4 + i][bt * 16 + l15] = acc[at][bt][i];
    __syncthreads();
    float ss = 0.f;
    for (int e = tid * 16; e < tid * 16 + 16; ++e) {
        const int r = e >> 6, c = e & 63;
        const float gk = part[0][r][c] + part[1][r][c] + part[2][r][c] + part[3][r][c];
        ss += gk * gq[r][c];
    }
#pragma unroll
    for (int mk = 1; mk < 64; mk <<= 1) ss += __shfl_xor(ss, mk);
    if (l == 0) red[w] = ss;
    __syncthreads();
    if (tid == 0) {
        const float S = red[0] + red[1] + red[2] + red[3];
        const float a = alpha_p[0];
        cscale[b] = a / (sqrtf(a * a * S) + 1e-5f);
    }
}

// ---------------------------------------------------------------------------
// Flash attention, fixed-anchor softmax (no max tracking / rescale):
// p = exp(score/8 - 16); final O = sum(p*V)/sum(p) is anchor-invariant.
// grid 1024 = 64 bh x 16 q-splits of 64 rows (XCD decode: same-bh -> same XCD).
// 4 waves x 16 q-rows, kv-tiles of 64 dbuf'd in LDS, tiles >= vl skipped.
// LDS 40KB -> 4 blocks/CU. Epilogue adds X = qm @ U^T * cscale.
// ---------------------------------------------------------------------------
__global__ __launch_bounds__(256, 4) void attn_kernel(const unsigned short* qh, const unsigned short* kh,
                                                      const unsigned short* vht, const unsigned short* U,
                                                      const float* cscale, const float* qm,
                                                      const int* valid_lens, unsigned short* aout) {
    const int wg = blockIdx.x;
    const int xcd = wg & 7, ii = wg >> 3;
    const int bh = (ii >> 4) * 8 + xcd;
    const int q0 = (ii & 15) * 64;
    const int b = bh >> 4, h = bh & 15;
    const int tid = threadIdx.x, l = tid & 63, w = tid >> 6;
    const int l15 = l & 15, lq = l >> 4;
    const int vl = valid_lens[b];
    const float cs = cscale[b];
    const int ntile = (vl + 63) >> 6;

    __shared__ unsigned short Kt[2][64][64];   // [buf][key][dh], granule^=(key&7)
    __shared__ unsigned short Vt[2][64][64];   // [buf][dh][key], granule^=(dh&7)
    __shared__ unsigned short Pl[4][16][64];   // per-wave P, col^=(8*(row&7))

    const int sr = l >> 3;                     // lane row within 8-row chunk
    const int gs = (l & 7) ^ (sr & 7);         // pre-swizzled source granule
    const unsigned short* khb = kh + (size_t)bh * SB * DHD;
    const unsigned short* vhb = vht + (size_t)bh * DHD * SB;

    auto STAGE = [&](int bb, int t) {
        const int kv0 = t << 6;
        const int r1 = w * 8 + sr, r2 = r1 + 32;
        gload_lds16(khb + (size_t)(kv0 + r1) * DHD + gs * 8, &Kt[bb][w * 8][0]);
        gload_lds16(khb + (size_t)(kv0 + r2) * DHD + gs * 8, &Kt[bb][w * 8 + 32][0]);
        gload_lds16(vhb + (size_t)r1 * SB + kv0 + gs * 8, &Vt[bb][w * 8][0]);
        gload_lds16(vhb + (size_t)r2 * SB + kv0 + gs * 8, &Vt[bb][w * 8 + 32][0]);
    };

    // Q fragments for this wave's 16 rows
    s16x8 aq[2];
#pragma unroll
    for (int kt = 0; kt < 2; ++kt)
        aq[kt] = *(const s16x8*)(qh + ((size_t)bh * SB + q0 + w * 16 + l15) * DHD + kt * 32 + 8 * lq);

    float l_[4];
    f32x4 oacc[4];
#pragma unroll
    for (int i = 0; i < 4; ++i) l_[i] = 0.f;
#pragma unroll
    for (int nd = 0; nd < 4; ++nd) oacc[nd] = (f32x4){0.f, 0.f, 0.f, 0.f};

    STAGE(0, 0);
    __syncthreads();
    int cur = 0;
    for (int t = 0; t < ntile; ++t) {
        if (t + 1 < ntile) STAGE(cur ^ 1, t + 1);
        const int kv0 = t << 6;
        const bool bdry = (kv0 + 64 > vl);

        // ---- QK^T (B-frags from swizzled Kt) ----
        f32x4 sc[4];
#pragma unroll
        for (int nt = 0; nt < 4; ++nt) {
            const int r = nt * 16 + l15;
            s16x8 b0 = *(const s16x8*)(&Kt[cur][r][((lq) ^ (r & 7)) * 8]);
            s16x8 b1 = *(const s16x8*)(&Kt[cur][r][((4 + lq) ^ (r & 7)) * 8]);
            f32x4 z = (f32x4){0.f, 0.f, 0.f, 0.f};
            z = __builtin_amdgcn_mfma_f32_16x16x32_bf16(aq[0], b0, z, 0, 0, 0);
            sc[nt] = __builtin_amdgcn_mfma_f32_16x16x32_bf16(aq[1], b1, z, 0, 0, 0);
        }

        // ---- p = exp(s/8 - 16) (fixed anchor), accumulate l, write P ----
#pragma unroll
        for (int nt = 0; nt < 4; ++nt) {
            const bool ok = !bdry || (kv0 + nt * 16 + l15 < vl);
#pragma unroll
            for (int i = 0; i < 4; ++i) {
                const float p = ok ? __expf(sc[nt][i] * 0.125f - 16.f) : 0.f;
                l_[i] += p;
                const int pr = lq * 4 + i;
                Pl[w][pr][(nt * 16 + l15) ^ (8 * (pr & 7))] = f2bf(p);
            }
        }

        // ---- PV accumulate ----
#pragma unroll
        for (int kt = 0; kt < 2; ++kt) {
            s16x8 pa = *(const s16x8*)(&Pl[w][l15][((kt * 4 + lq) ^ (l15 & 7)) * 8]);
#pragma unroll
            for (int nd = 0; nd < 4; ++nd) {
                const int r = nd * 16 + l15;
                s16x8 vb = *(const s16x8*)(&Vt[cur][r][((kt * 4 + lq) ^ (r & 7)) * 8]);
                oacc[nd] = __builtin_amdgcn_mfma_f32_16x16x32_bf16(pa, vb, oacc[nd], 0, 0, 0);
            }
        }
        __syncthreads();
        cur ^= 1;
    }

    // reduce lane-partial softmax denominators across the 16 lanes of each row
#pragma unroll
    for (int mk = 1; mk < 16; mk <<= 1)
#pragma unroll
        for (int i = 0; i < 4; ++i) l_[i] += __shfl_xor(l_[i], mk);

    // ---- epilogue: X = qm @ U^T, out = O/l + X*cs ----
    s16x8 xa[2];
#pragma unroll
    for (int kt2 = 0; kt2 < 2; ++kt2) {
        const float* qp = qm + ((size_t)b * SB + q0 + w * 16 + l15) * MM + kt2 * 32 + 8 * lq;
        f32x4 qa = *(const f32x4*)qp;
        f32x4 qb2 = *(const f32x4*)(qp + 4);
        s16x8 at;
        at[0] = (short)f2bf(qa[0]);  at[1] = (short)f2bf(qa[1]);
        at[2] = (short)f2bf(qa[2]);  at[3] = (short)f2bf(qa[3]);
        at[4] = (short)f2bf(qb2[0]); at[5] = (short)f2bf(qb2[1]);
        at[6] = (short)f2bf(qb2[2]); at[7] = (short)f2bf(qb2[3]);
        xa[kt2] = at;
    }
    float rinv[4];
#pragma unroll
    for (int i = 0; i < 4; ++i) rinv[i] = 1.f / l_[i];
#pragma unroll
    for (int nd = 0; nd < 4; ++nd) {
        f32x4 xacc = (f32x4){0.f, 0.f, 0.f, 0.f};
#pragma unroll
        for (int kt2 = 0; kt2 < 2; ++kt2) {
            s16x8 bu = *(const s16x8*)(U + ((size_t)bh * 64 + nd * 16 + l15) * 64 + kt2 * 32 + 8 * lq);
            xacc = __builtin_amdgcn_mfma_f32_16x16x32_bf16(xa[kt2], bu, xacc, 0, 0, 0);
        }
#pragma unroll
        for (int i = 0; i < 4; ++i) {
            const int row = q0 + w * 16 + lq * 4 + i;
            const float val = oacc[nd][i] * rinv[i] + xacc[i] * cs;
            aout[((size_t)b * SB + row) * DD + h * DHD + nd * 16 + l15] = f2bf(val);
        }
    }
}

// ---------------------------------------------------------------------------
extern "C" void kernel_launch(void* const* d_in, const int* in_sizes, int n_in,
                              void* d_out, int out_size, void* d_ws, size_t ws_size,
                              hipStream_t stream) {
    const float* q   = (const float*)d_in[0];
    const float* k   = (const float*)d_in[1];
    const float* v   = (const float*)d_in[2];
    const float* qm  = (const float*)d_in[3];
    const float* kvm = (const float*)d_in[4];
    const int* vl    = (const int*)d_in[5];
    const float* Wq  = (const float*)d_in[6];
    const float* Wk  = (const float*)d_in[7];
    const float* Wv  = (const float*)d_in[8];
    const float* Wo  = (const float*)d_in[9];
    const float* alpha = (const float*)d_in[10];

    char* ws = (char*)d_ws;
    unsigned short* Wt  = (unsigned short*)(ws);                        // 0..8MB
    unsigned short* qb  = (unsigned short*)(ws + ((size_t)8  << 20));   // 8..16MB
    unsigned short* kb  = (unsigned short*)(ws + ((size_t)16 << 20));   // 16..24MB
    unsigned short* vb  = (unsigned short*)(ws + ((size_t)24 << 20));   // 24..32MB
    unsigned short* qhp = (unsigned short*)(ws + ((size_t)32 << 20));   // 32..40MB
    unsigned short* khp = (unsigned short*)(ws + ((size_t)40 << 20));   // 40..48MB
    unsigned short* vht = (unsigned short*)(ws + ((size_t)48 << 20));   // 48..56MB
    unsigned short* U   = (unsigned short*)(ws + ((size_t)8  << 20));   // reuse qb (dead)
    float* csc          = (float*)(ws + ((size_t)9 << 20));             // 16B
    unsigned short* aout = (unsigned short*)(ws + ((size_t)16 << 20));  // reuse kb (dead)

    cvt_kernel<<<dim3(2048, 3, 1), 256, 0, stream>>>(q, k, v, qb, kb, vb);
    wtrans_kernel<<<dim3(32, 32, 4), dim3(32, 8, 1), 0, stream>>>(Wq, Wk, Wv, Wo, Wt);

    gemm_qkv_kernel<<<768, 512, 0, stream>>>(qb, kb, vb, Wt, qhp, khp, vht);

    uk_kernel<<<64, 256, 0, stream>>>(vht, kvm, U);
    gram_kernel<<<4, 256, 0, stream>>>(qm, kvm, alpha, csc);

    attn_kernel<<<1024, 256, 0, stream>>>(qhp, khp, vht, U, csc, qm, vl, aout);
    gemm_o_kernel<<<256, 512, 0, stream>>>(aout, Wt + 3 * (1u << 20), (float*)d_out);
}

// Round 7
// 212.399 us; speedup vs baseline: 1.9616x; 1.1220x over previous
//
#include <hip/hip_runtime.h>
#include <hip/hip_bf16.h>
#include <stdint.h>

// B=4, S=1024, D=1024, H=16, M=64, DH=64
#define SB 1024
#define DD 1024
#define NH 16
#define MM 64
#define DHD 64

typedef __attribute__((ext_vector_type(8))) short s16x8;
typedef __attribute__((ext_vector_type(4))) float f32x4;

__device__ __forceinline__ unsigned short f2bf(float f) {
    union { float f; unsigned int u; } v; v.f = f;
    unsigned int u = v.u;
    u += 0x7FFFu + ((u >> 16) & 1u);
    return (unsigned short)(u >> 16);
}

__device__ __forceinline__ void gload_lds16(const unsigned short* g, unsigned short* l) {
    __builtin_amdgcn_global_load_lds(
        (const __attribute__((address_space(1))) unsigned int*)g,
        (__attribute__((address_space(3))) unsigned int*)l, 16, 0, 0);
}

// ---------------------------------------------------------------------------
// Merged: q/k/v f32->bf16 (blocks 0..6143) + W transpose/convert (6144..10239).
// ---------------------------------------------------------------------------
__global__ __launch_bounds__(256) void cvtw_kernel(const float* q, const float* k, const float* v,
                                                   unsigned short* qb, unsigned short* kb,
                                                   unsigned short* vb,
                                                   const float* W0, const float* W1,
                                                   const float* W2, const float* W3,
                                                   unsigned short* Wt) {
    const int bid = blockIdx.x, tid = threadIdx.x;
    __shared__ float tile[32][33];
    if (bid < 6144) {
        const int z = bid >> 11;
        const float* src = (z == 0) ? q : (z == 1) ? k : v;
        unsigned short* dst = (z == 0) ? qb : (z == 1) ? kb : vb;
        const size_t base = ((size_t)(bid & 2047) * 256 + tid) * 8;
        f32x4 a = *(const f32x4*)(src + base);
        f32x4 b2 = *(const f32x4*)(src + base + 4);
        s16x8 t;
        t[0] = (short)f2bf(a[0]);  t[1] = (short)f2bf(a[1]);
        t[2] = (short)f2bf(a[2]);  t[3] = (short)f2bf(a[3]);
        t[4] = (short)f2bf(b2[0]); t[5] = (short)f2bf(b2[1]);
        t[6] = (short)f2bf(b2[2]); t[7] = (short)f2bf(b2[3]);
        *(s16x8*)(dst + base) = t;
    } else {
        const int wt = bid - 6144;
        const int z = wt >> 10, rem = wt & 1023;
        const int x0 = (rem & 31) * 32, y0 = (rem >> 5) * 32;
        const float* W = (z == 0) ? W0 : (z == 1) ? W1 : (z == 2) ? W2 : W3;
        unsigned short* Wo_ = Wt + (size_t)z * DD * DD;
        const int tx = tid & 31, ty = tid >> 5;
#pragma unroll
        for (int j = 0; j < 4; ++j)
            tile[ty + 8 * j][tx] = W[(size_t)(y0 + ty + 8 * j) * DD + x0 + tx];
        __syncthreads();
#pragma unroll
        for (int j = 0; j < 4; ++j)
            Wo_[(size_t)(x0 + ty + 8 * j) * DD + y0 + tx] = f2bf(tile[tx][ty + 8 * j]);
    }
}

// ---------------------------------------------------------------------------
// GEMM body: C[128x128 tile at (m0b,n0b)] = A @ Bt^T, bf16 MFMA, BK=64,
// 512 threads, gload_lds(16) + XOR-swizzled source, double-buffered.
// LDS tile passed in by the kernel (single allocation across instantiations).
// OMODE 0: head-split bf16; 1: v-transposed bf16; 2: f32 flat.
// ---------------------------------------------------------------------------
typedef unsigned short LdsTile[2][2][128][64];

template <int OMODE>
__device__ __forceinline__ void gemm_body(const unsigned short* A, const unsigned short* Bt,
                                          void* outp, int m0b, int n0b, LdsTile& lds) {
    const int tid = threadIdx.x, l = tid & 63, w = tid >> 6;
    const int l15 = l & 15, lq = l >> 4;
    const int wm = (w >> 1) * 32, wn = (w & 1) * 64;
    const int ric = l >> 3;
    const int gsrc = (l & 7) ^ (ric & 7);

    f32x4 acc[2][4];
#pragma unroll
    for (int i = 0; i < 2; ++i)
#pragma unroll
        for (int j = 0; j < 4; ++j) acc[i][j] = (f32x4){0.f, 0.f, 0.f, 0.f};

    auto STAGE = [&](int bb, int kt) {
        const int k0 = kt * 64;
#pragma unroll
        for (int j = 0; j < 2; ++j) {
            const int chunk = w * 2 + j;
            const int r = chunk * 8 + ric;
            gload_lds16(A + (size_t)(m0b + r) * DD + k0 + gsrc * 8, &lds[bb][0][chunk * 8][0]);
            gload_lds16(Bt + (size_t)(n0b + r) * DD + k0 + gsrc * 8, &lds[bb][1][chunk * 8][0]);
        }
    };

    STAGE(0, 0);
    __syncthreads();
    int cur = 0;
    for (int kt = 0; kt < 16; ++kt) {
        if (kt < 15) STAGE(cur ^ 1, kt + 1);
#pragma unroll
        for (int kt2 = 0; kt2 < 2; ++kt2) {
            s16x8 af[2], bf[4];
#pragma unroll
            for (int mi = 0; mi < 2; ++mi) {
                const int R = wm + mi * 16 + l15;
                af[mi] = *(const s16x8*)(&lds[cur][0][R][((kt2 * 4 + lq) ^ (R & 7)) * 8]);
            }
#pragma unroll
            for (int ni = 0; ni < 4; ++ni) {
                const int R = wn + ni * 16 + l15;
                bf[ni] = *(const s16x8*)(&lds[cur][1][R][((kt2 * 4 + lq) ^ (R & 7)) * 8]);
            }
#pragma unroll
            for (int mi = 0; mi < 2; ++mi)
#pragma unroll
                for (int ni = 0; ni < 4; ++ni)
                    acc[mi][ni] = __builtin_amdgcn_mfma_f32_16x16x32_bf16(af[mi], bf[ni],
                                                                          acc[mi][ni], 0, 0, 0);
        }
        __syncthreads();
        cur ^= 1;
    }

#pragma unroll
    for (int mi = 0; mi < 2; ++mi)
#pragma unroll
        for (int ni = 0; ni < 4; ++ni)
#pragma unroll
            for (int i = 0; i < 4; ++i) {
                const int r = m0b + wm + mi * 16 + lq * 4 + i;
                const int c = n0b + wn + ni * 16 + l15;
                const float vv = acc[mi][ni][i];
                if (OMODE == 2) {
                    ((float*)outp)[(size_t)r * DD + c] = vv;
                } else {
                    const int b = r >> 10, s = r & 1023;
                    const int hh = c >> 6, dh = c & 63;
                    if (OMODE == 0)
                        ((unsigned short*)outp)[((size_t)((b * NH + hh) * SB + s)) * DHD + dh] = f2bf(vv);
                    else
                        ((unsigned short*)outp)[((size_t)((b * NH + hh) * DHD + dh)) * SB + s] = f2bf(vv);
                }
            }
}

// XCD-aware decode: 256 blocks/tensor; 4 consecutive A-panels + whole B per XCD
// -> per-XCD L2 working set ~3MB (fits 4MB).
__device__ __forceinline__ void xcd_decode(int i, int& m0b, int& n0b) {
    const int xcd = i & 7, idx = i >> 3;
    m0b = (xcd * 4 + (idx >> 3)) * 128;
    n0b = (idx & 7) * 128;
}

// Fused QKV projections: grid 768 = 3 tensors x 256 tiles.
__global__ __launch_bounds__(512, 4) void gemm_qkv_kernel(const unsigned short* qb,
                                                          const unsigned short* kb,
                                                          const unsigned short* vb,
                                                          const unsigned short* Wt,
                                                          unsigned short* qhp, unsigned short* khp,
                                                          unsigned short* vht) {
    __shared__ LdsTile lds;
    const int wg = blockIdx.x;
    const int t = wg >> 8, i = wg & 255;
    int m0b, n0b;
    xcd_decode(i, m0b, n0b);
    const unsigned short* Bt = Wt + (size_t)t * DD * DD;
    if (t == 0)      gemm_body<0>(qb, Bt, qhp, m0b, n0b, lds);
    else if (t == 1) gemm_body<0>(kb, Bt, khp, m0b, n0b, lds);
    else             gemm_body<1>(vb, Bt, vht, m0b, n0b, lds);
}

// Output projection: grid 256.
__global__ __launch_bounds__(512, 4) void gemm_o_kernel(const unsigned short* aout,
                                                        const unsigned short* WtO, float* out) {
    __shared__ LdsTile lds;
    int m0b, n0b;
    xcd_decode(blockIdx.x, m0b, n0b);
    gemm_body<2>(aout, WtO, out, m0b, n0b, lds);
}

// ---------------------------------------------------------------------------
// Merged uk+gram. Blocks 0..63: U[bh] = vht[bh] @ kvm[b]  (bf16 [dh][m]).
// Blocks 64..67: cscale[b] = alpha / (sqrt(alpha^2 * sum(Gq o Gk)) + 1e-5).
// ---------------------------------------------------------------------------
__global__ __launch_bounds__(256) void ukgram_kernel(const unsigned short* vht, const float* qm,
                                                     const float* kvm, const float* alpha_p,
                                                     unsigned short* U, float* cscale) {
    __shared__ char lds_raw[81952];
    float (*part)[64][64] = (float (*)[64][64])lds_raw;          // 64KB
    float (*gq)[64] = (float (*)[64])(lds_raw + 65536);          // 16KB
    float* red = (float*)(lds_raw + 81920);                      // 16B+

    const int bid = blockIdx.x;
    const int tid = threadIdx.x, l = tid & 63, w = tid >> 6;
    const int l15 = l & 15, lq = l >> 4;

    if (bid < 64) {
        const int bh = bid, b = bh >> 4;
        f32x4 acc[4][4];
#pragma unroll
        for (int i = 0; i < 4; ++i)
#pragma unroll
            for (int j = 0; j < 4; ++j) acc[i][j] = (f32x4){0.f, 0.f, 0.f, 0.f};
        for (int kt2 = 0; kt2 < 8; ++kt2) {
            const int sbase = w * 256 + kt2 * 32 + 8 * lq;
            s16x8 av[4], bk[4];
#pragma unroll
            for (int t = 0; t < 4; ++t)
                av[t] = *(const s16x8*)(vht + ((size_t)bh * DHD + t * 16 + l15) * SB + sbase);
#pragma unroll
            for (int t = 0; t < 4; ++t) {
                s16x8 tmp;
#pragma unroll
                for (int j = 0; j < 8; ++j)
                    tmp[j] = (short)f2bf(kvm[((size_t)b * SB + sbase + j) * MM + t * 16 + l15]);
                bk[t] = tmp;
            }
#pragma unroll
            for (int at = 0; at < 4; ++at)
#pragma unroll
                for (int bt = 0; bt < 4; ++bt)
                    acc[at][bt] = __builtin_amdgcn_mfma_f32_16x16x32_bf16(av[at], bk[bt],
                                                                          acc[at][bt], 0, 0, 0);
        }
#pragma unroll
        for (int at = 0; at < 4; ++at)
#pragma unroll
            for (int bt = 0; bt < 4; ++bt)
#pragma unroll
                for (int i = 0; i < 4; ++i)
                    part[w][at * 16 + lq * 4 + i][bt * 16 + l15] = acc[at][bt][i];
        __syncthreads();
        for (int e = tid * 16; e < tid * 16 + 16; ++e) {
            const int r = e >> 6, c = e & 63;
            U[(size_t)bh * 4096 + e] =
                f2bf(part[0][r][c] + part[1][r][c] + part[2][r][c] + part[3][r][c]);
        }
    } else {
        const int b = bid - 64;
        f32x4 acc[4][4];
        // phase 1: Gq
#pragma unroll
        for (int i = 0; i < 4; ++i)
#pragma unroll
            for (int j = 0; j < 4; ++j) acc[i][j] = (f32x4){0.f, 0.f, 0.f, 0.f};
        for (int kt2 = 0; kt2 < 8; ++kt2) {
            const int sbase = w * 256 + kt2 * 32 + 8 * lq;
            s16x8 fq[4];
#pragma unroll
            for (int t = 0; t < 4; ++t) {
                s16x8 tmp;
#pragma unroll
                for (int j = 0; j < 8; ++j)
                    tmp[j] = (short)f2bf(qm[((size_t)b * SB + sbase + j) * MM + t * 16 + l15]);
                fq[t] = tmp;
            }
#pragma unroll
            for (int at = 0; at < 4; ++at)
#pragma unroll
                for (int bt = 0; bt < 4; ++bt)
                    acc[at][bt] = __builtin_amdgcn_mfma_f32_16x16x32_bf16(fq[at], fq[bt],
                                                                         acc[at][bt], 0, 0, 0);
        }
#pragma unroll
        for (int at = 0; at < 4; ++at)
#pragma unroll
            for (int bt = 0; bt < 4; ++bt)
#pragma unroll
                for (int i = 0; i < 4; ++i)
                    part[w][at * 16 + lq * 4 + i][bt * 16 + l15] = acc[at][bt][i];
        __syncthreads();
        for (int e = tid * 16; e < tid * 16 + 16; ++e) {
            const int r = e >> 6, c = e & 63;
            gq[r][c] = part[0][r][c] + part[1][r][c] + part[2][r][c] + part[3][r][c];
        }
        __syncthreads();
        // phase 2: Gk + dot with Gq
#pragma unroll
        for (int i = 0; i < 4; ++i)
#pragma unroll
            for (int j = 0; j < 4; ++j) acc[i][j] = (f32x4){0.f, 0.f, 0.f, 0.f};
        for (int kt2 = 0; kt2 < 8; ++kt2) {
            const int sbase = w * 256 + kt2 * 32 + 8 * lq;
            s16x8 fk[4];
#pragma unroll
            for (int t = 0; t < 4; ++t) {
                s16x8 tmp;
#pragma unroll
                for (int j = 0; j < 8; ++j)
                    tmp[j] = (short)f2bf(kvm[((size_t)b * SB + sbase + j) * MM + t * 16 + l15]);
                fk[t] = tmp;
            }
#pragma unroll
            for (int at = 0; at < 4; ++at)
#pragma unroll
                for (int bt = 0; bt < 4; ++bt)
                    acc[at][bt] = __builtin_amdgcn_mfma_f32_16x16x32_bf16(fk[at], fk[bt],
                                                                         acc[at][bt], 0, 0, 0);
        }
#pragma unroll
        for (int at = 0; at < 4; ++at)
#pragma unroll
            for (int bt = 0; bt < 4; ++bt)
#pragma unroll
                for (int i = 0; i < 4; ++i)
                    part[w][at * 16 + lq * 4 + i][bt * 16 + l15] = acc[at][bt][i];
        __syncthreads();
        float ss = 0.f;
        for (int e = tid * 16; e < tid * 16 + 16; ++e) {
            const int r = e >> 6, c = e & 63;
            const float gk = part[0][r][c] + part[1][r][c] + part[2][r][c] + part[3][r][c];
            ss += gk * gq[r][c];
        }
#pragma unroll
        for (int mk = 1; mk < 64; mk <<= 1) ss += __shfl_xor(ss, mk);
        if (l == 0) red[w] = ss;
        __syncthreads();
        if (tid == 0) {
            const float S = red[0] + red[1] + red[2] + red[3];
            const float a = alpha_p[0];
            cscale[b] = a / (sqrtf(a * a * S) + 1e-5f);
        }
    }
}

// ---------------------------------------------------------------------------
// Flash attention, fixed-anchor softmax (no max tracking / rescale):
// p = exp(score/8 - 16); final O = sum(p*V)/sum(p) is anchor-invariant.
// grid 1024 = 64 bh x 16 q-splits of 64 rows (XCD decode: same-bh -> same XCD).
// 4 waves x 16 q-rows, kv-tiles of 64 dbuf'd in LDS, tiles >= vl skipped.
// LDS 40KB -> 4 blocks/CU. Epilogue adds X = qm @ U^T * cscale.
// ---------------------------------------------------------------------------
__global__ __launch_bounds__(256, 4) void attn_kernel(const unsigned short* qh, const unsigned short* kh,
                                                      const unsigned short* vht, const unsigned short* U,
                                                      const float* cscale, const float* qm,
                                                      const int* valid_lens, unsigned short* aout) {
    const int wg = blockIdx.x;
    const int xcd = wg & 7, ii = wg >> 3;
    const int bh = (ii >> 4) * 8 + xcd;
    const int q0 = (ii & 15) * 64;
    const int b = bh >> 4, h = bh & 15;
    const int tid = threadIdx.x, l = tid & 63, w = tid >> 6;
    const int l15 = l & 15, lq = l >> 4;
    const int vl = valid_lens[b];
    const float cs = cscale[b];
    const int ntile = (vl + 63) >> 6;

    __shared__ unsigned short Kt[2][64][64];   // [buf][key][dh], granule^=(key&7)
    __shared__ unsigned short Vt[2][64][64];   // [buf][dh][key], granule^=(dh&7)
    __shared__ unsigned short Pl[4][16][64];   // per-wave P, col^=(8*(row&7))

    const int sr = l >> 3;                     // lane row within 8-row chunk
    const int gs = (l & 7) ^ (sr & 7);         // pre-swizzled source granule
    const unsigned short* khb = kh + (size_t)bh * SB * DHD;
    const unsigned short* vhb = vht + (size_t)bh * DHD * SB;

    auto STAGE = [&](int bb, int t) {
        const int kv0 = t << 6;
        const int r1 = w * 8 + sr, r2 = r1 + 32;
        gload_lds16(khb + (size_t)(kv0 + r1) * DHD + gs * 8, &Kt[bb][w * 8][0]);
        gload_lds16(khb + (size_t)(kv0 + r2) * DHD + gs * 8, &Kt[bb][w * 8 + 32][0]);
        gload_lds16(vhb + (size_t)r1 * SB + kv0 + gs * 8, &Vt[bb][w * 8][0]);
        gload_lds16(vhb + (size_t)r2 * SB + kv0 + gs * 8, &Vt[bb][w * 8 + 32][0]);
    };

    // Q fragments for this wave's 16 rows
    s16x8 aq[2];
#pragma unroll
    for (int kt = 0; kt < 2; ++kt)
        aq[kt] = *(const s16x8*)(qh + ((size_t)bh * SB + q0 + w * 16 + l15) * DHD + kt * 32 + 8 * lq);

    float l_[4];
    f32x4 oacc[4];
#pragma unroll
    for (int i = 0; i < 4; ++i) l_[i] = 0.f;
#pragma unroll
    for (int nd = 0; nd < 4; ++nd) oacc[nd] = (f32x4){0.f, 0.f, 0.f, 0.f};

    STAGE(0, 0);
    __syncthreads();
    int cur = 0;
    for (int t = 0; t < ntile; ++t) {
        if (t + 1 < ntile) STAGE(cur ^ 1, t + 1);
        const int kv0 = t << 6;
        const bool bdry = (kv0 + 64 > vl);

        // ---- QK^T (B-frags from swizzled Kt) ----
        f32x4 sc[4];
#pragma unroll
        for (int nt = 0; nt < 4; ++nt) {
            const int r = nt * 16 + l15;
            s16x8 b0 = *(const s16x8*)(&Kt[cur][r][((lq) ^ (r & 7)) * 8]);
            s16x8 b1 = *(const s16x8*)(&Kt[cur][r][((4 + lq) ^ (r & 7)) * 8]);
            f32x4 z = (f32x4){0.f, 0.f, 0.f, 0.f};
            z = __builtin_amdgcn_mfma_f32_16x16x32_bf16(aq[0], b0, z, 0, 0, 0);
            sc[nt] = __builtin_amdgcn_mfma_f32_16x16x32_bf16(aq[1], b1, z, 0, 0, 0);
        }

        // ---- p = exp(s/8 - 16) (fixed anchor), accumulate l, write P ----
#pragma unroll
        for (int nt = 0; nt < 4; ++nt) {
            const bool ok = !bdry || (kv0 + nt * 16 + l15 < vl);
#pragma unroll
            for (int i = 0; i < 4; ++i) {
                const float p = ok ? __expf(sc[nt][i] * 0.125f - 16.f) : 0.f;
                l_[i] += p;
                const int pr = lq * 4 + i;
                Pl[w][pr][(nt * 16 + l15) ^ (8 * (pr & 7))] = f2bf(p);
            }
        }

        // ---- PV accumulate ----
#pragma unroll
        for (int kt = 0; kt < 2; ++kt) {
            s16x8 pa = *(const s16x8*)(&Pl[w][l15][((kt * 4 + lq) ^ (l15 & 7)) * 8]);
#pragma unroll
            for (int nd = 0; nd < 4; ++nd) {
                const int r = nd * 16 + l15;
                s16x8 vb = *(const s16x8*)(&Vt[cur][r][((kt * 4 + lq) ^ (r & 7)) * 8]);
                oacc[nd] = __builtin_amdgcn_mfma_f32_16x16x32_bf16(pa, vb, oacc[nd], 0, 0, 0);
            }
        }
        __syncthreads();
        cur ^= 1;
    }

    // reduce lane-partial softmax denominators across the 16 lanes of each row
#pragma unroll
    for (int mk = 1; mk < 16; mk <<= 1)
#pragma unroll
        for (int i = 0; i < 4; ++i) l_[i] += __shfl_xor(l_[i], mk);

    // ---- epilogue: X = qm @ U^T, out = O/l + X*cs ----
    s16x8 xa[2];
#pragma unroll
    for (int kt2 = 0; kt2 < 2; ++kt2) {
        const float* qp = qm + ((size_t)b * SB + q0 + w * 16 + l15) * MM + kt2 * 32 + 8 * lq;
        f32x4 qa = *(const f32x4*)qp;
        f32x4 qb2 = *(const f32x4*)(qp + 4);
        s16x8 at;
        at[0] = (short)f2bf(qa[0]);  at[1] = (short)f2bf(qa[1]);
        at[2] = (short)f2bf(qa[2]);  at[3] = (short)f2bf(qa[3]);
        at[4] = (short)f2bf(qb2[0]); at[5] = (short)f2bf(qb2[1]);
        at[6] = (short)f2bf(qb2[2]); at[7] = (short)f2bf(qb2[3]);
        xa[kt2] = at;
    }
    float rinv[4];
#pragma unroll
    for (int i = 0; i < 4; ++i) rinv[i] = 1.f / l_[i];
#pragma unroll
    for (int nd = 0; nd < 4; ++nd) {
        f32x4 xacc = (f32x4){0.f, 0.f, 0.f, 0.f};
#pragma unroll
        for (int kt2 = 0; kt2 < 2; ++kt2) {
            s16x8 bu = *(const s16x8*)(U + ((size_t)bh * 64 + nd * 16 + l15) * 64 + kt2 * 32 + 8 * lq);
            xacc = __builtin_amdgcn_mfma_f32_16x16x32_bf16(xa[kt2], bu, xacc, 0, 0, 0);
        }
#pragma unroll
        for (int i = 0; i < 4; ++i) {
            const int row = q0 + w * 16 + lq * 4 + i;
            const float val = oacc[nd][i] * rinv[i] + xacc[i] * cs;
            aout[((size_t)b * SB + row) * DD + h * DHD + nd * 16 + l15] = f2bf(val);
        }
    }
}

// ---------------------------------------------------------------------------
extern "C" void kernel_launch(void* const* d_in, const int* in_sizes, int n_in,
                              void* d_out, int out_size, void* d_ws, size_t ws_size,
                              hipStream_t stream) {
    const float* q   = (const float*)d_in[0];
    const float* k   = (const float*)d_in[1];
    const float* v   = (const float*)d_in[2];
    const float* qm  = (const float*)d_in[3];
    const float* kvm = (const float*)d_in[4];
    const int* vl    = (const int*)d_in[5];
    const float* Wq  = (const float*)d_in[6];
    const float* Wk  = (const float*)d_in[7];
    const float* Wv  = (const float*)d_in[8];
    const float* Wo  = (const float*)d_in[9];
    const float* alpha = (const float*)d_in[10];

    char* ws = (char*)d_ws;
    unsigned short* Wt  = (unsigned short*)(ws);                        // 0..8MB
    unsigned short* qb  = (unsigned short*)(ws + ((size_t)8  << 20));   // 8..16MB
    unsigned short* kb  = (unsigned short*)(ws + ((size_t)16 << 20));   // 16..24MB
    unsigned short* vb  = (unsigned short*)(ws + ((size_t)24 << 20));   // 24..32MB
    unsigned short* qhp = (unsigned short*)(ws + ((size_t)32 << 20));   // 32..40MB
    unsigned short* khp = (unsigned short*)(ws + ((size_t)40 << 20));   // 40..48MB
    unsigned short* vht = (unsigned short*)(ws + ((size_t)48 << 20));   // 48..56MB
    unsigned short* U   = (unsigned short*)(ws + ((size_t)8  << 20));   // reuse qb (dead)
    float* csc          = (float*)(ws + ((size_t)9 << 20));             // 16B
    unsigned short* aout = (unsigned short*)(ws + ((size_t)16 << 20));  // reuse kb (dead)

    cvtw_kernel<<<10240, 256, 0, stream>>>(q, k, v, qb, kb, vb, Wq, Wk, Wv, Wo, Wt);
    gemm_qkv_kernel<<<768, 512, 0, stream>>>(qb, kb, vb, Wt, qhp, khp, vht);
    ukgram_kernel<<<68, 256, 0, stream>>>(vht, qm, kvm, alpha, U, csc);
    attn_kernel<<<1024, 256, 0, stream>>>(qhp, khp, vht, U, csc, qm, vl, aout);
    gemm_o_kernel<<<256, 512, 0, stream>>>(aout, Wt + 3 * (1u << 20), (float*)d_out);
}